// Round 1
// baseline (2917.944 us; speedup 1.0000x reference)
//
#include <hip/hip_runtime.h>
#include <hip/hip_bf16.h>
#include <math.h>

#define NBATCH 8
#define HWP 4096
#define NTOK 32768
#define CIN 128
#define HID 256
#define MLPH 2048
#define SLOTF 8388608L   // floats per 32MB slot

typedef unsigned short u16;

__device__ __forceinline__ float bf2f(u16 v) { return __uint_as_float(((unsigned)v) << 16); }
__device__ __forceinline__ u16 f2bf(float f) {
    unsigned u = __float_as_uint(f);
    u = u + 0x7fffu + ((u >> 16) & 1u);
    return (u16)(u >> 16);
}
__device__ __forceinline__ float sshrink(float v) {
    return v > 0.01f ? v - 0.01f : (v < -0.01f ? v + 0.01f : 0.f);
}

// ---------------- LN1: x (B,128,4096) -> xn (B*4096,128) ----------------
__global__ __launch_bounds__(256) void ln1_kernel(const float* __restrict__ x,
    const float* __restrict__ g, const float* __restrict__ be, float* __restrict__ xn)
{
    __shared__ float xt[CIN][65];
    __shared__ float mu_s[64], rs_s[64];
    int bid = blockIdx.x;
    int b = bid >> 6;
    int t0 = (bid & 63) << 6;
    int tid = threadIdx.x;
    for (int it = 0; it < 32; ++it) {
        int idx = (it << 8) + tid;
        int c = idx >> 6, t = idx & 63;
        xt[c][t] = x[(long)(b * CIN + c) * HWP + t0 + t];
    }
    __syncthreads();
    int tt = tid >> 2, p = tid & 3;
    float s = 0.f, ss = 0.f;
    #pragma unroll
    for (int i = 0; i < 32; ++i) {
        float v = xt[p * 32 + i][tt];
        s += v; ss += v * v;
    }
    s += __shfl_xor(s, 1); ss += __shfl_xor(ss, 1);
    s += __shfl_xor(s, 2); ss += __shfl_xor(ss, 2);
    if (p == 0) {
        float mu = s * (1.f / CIN);
        float var = ss * (1.f / CIN) - mu * mu;
        mu_s[tt] = mu;
        rs_s[tt] = rsqrtf(var + 1e-5f);
    }
    __syncthreads();
    for (int it = 0; it < 32; ++it) {
        int idx = (it << 8) + tid;
        int t = idx >> 7, c = idx & 127;
        xn[((long)b * HWP + t0 + t) * CIN + c] = (xt[c][t] - mu_s[t]) * rs_s[t] * g[c] + be[c];
    }
}

// ---------------- residual GEMM: tok(B,T,128) @ proj_w(256,128)^T ----------------
__global__ __launch_bounds__(256) void resid_kernel(const float* __restrict__ x,
    const float* __restrict__ pw, const float* __restrict__ pb, float* __restrict__ res)
{
    __shared__ float xt[64][65];
    __shared__ float wt[64][65];
    int bid = blockIdx.x;
    int t0g = (bid >> 2) << 6;
    int o0 = (bid & 3) << 6;
    int b = t0g >> 12;
    int t0 = t0g & 4095;
    int tid = threadIdx.x;
    int tr = tid >> 4, tc = tid & 15;
    float acc[4][4] = {};
    for (int k0 = 0; k0 < CIN; k0 += 64) {
        __syncthreads();
        for (int it = 0; it < 16; ++it) {
            int idx = (it << 8) + tid;
            int r = idx >> 6, cc = idx & 63;
            xt[r][cc] = x[(long)(b * CIN + k0 + r) * HWP + t0 + cc];
            wt[r][cc] = pw[(o0 + r) * CIN + k0 + cc];
        }
        __syncthreads();
        #pragma unroll 8
        for (int k = 0; k < 64; ++k) {
            float a[4], w[4];
            #pragma unroll
            for (int i = 0; i < 4; ++i) a[i] = xt[k][tr * 4 + i];
            #pragma unroll
            for (int j = 0; j < 4; ++j) w[j] = wt[tc * 4 + j][k];
            #pragma unroll
            for (int i = 0; i < 4; ++i)
                #pragma unroll
                for (int j = 0; j < 4; ++j) acc[i][j] += a[i] * w[j];
        }
    }
    float pbv[4];
    #pragma unroll
    for (int j = 0; j < 4; ++j) pbv[j] = pb[o0 + tc * 4 + j];
    #pragma unroll
    for (int i = 0; i < 4; ++i) {
        float4 v = make_float4(acc[i][0] + pbv[0], acc[i][1] + pbv[1],
                               acc[i][2] + pbv[2], acc[i][3] + pbv[3]);
        *(float4*)&res[(long)(t0g + tr * 4 + i) * HID + o0 + tc * 4] = v;
    }
}

// ---------------- generic 64-point DFT along one axis ----------------
// in addr = b*inSB + keep*inSK + c*inSC + j*inSJ ; out addr = b*4096*C + keep*oSK + k*oSJ + c
template<bool CPLX>
__global__ __launch_bounds__(256) void dft64_kernel(
    const float* __restrict__ inR, const float* __restrict__ inI,
    float* __restrict__ outR, float* __restrict__ outI,
    int C, long inSB, long inSK, long inSC, long inSJ,
    long oSK, long oSJ, float sgn)
{
    __shared__ float lr[64][64];
    __shared__ float li[64][64];
    __shared__ float twr[64], twi[64];
    int cb = C >> 6;
    int bid = blockIdx.x;
    int b = bid / (64 * cb);
    int rem = bid % (64 * cb);
    int keep = rem / cb;
    int c0 = (rem % cb) << 6;
    int tid = threadIdx.x;
    if (tid < 64) {
        float sv, cv;
        sincosf(6.283185307179586f * (float)tid / 64.f, &sv, &cv);
        twr[tid] = cv; twi[tid] = sgn * sv;
    }
    long base = (long)b * inSB + (long)keep * inSK + (long)c0 * inSC;
    for (int it = 0; it < 16; ++it) {
        int idx = (it << 8) + tid;
        int j, c;
        if (inSJ == 1) { j = idx & 63; c = idx >> 6; }
        else           { c = idx & 63; j = idx >> 6; }
        long a = base + (long)c * inSC + (long)j * inSJ;
        lr[j][c] = inR[a];
        if (CPLX) li[j][c] = inI[a];
    }
    __syncthreads();
    int c = tid & 63;
    int kgrp = tid >> 6;
    float accR[16], accI[16];
    #pragma unroll
    for (int kk = 0; kk < 16; ++kk) { accR[kk] = 0.f; accI[kk] = 0.f; }
    for (int j = 0; j < 64; ++j) {
        float ar = lr[j][c];
        float ai = CPLX ? li[j][c] : 0.f;
        int m0 = (j * kgrp) & 63;
        int st = (j << 2) & 63;
        #pragma unroll
        for (int kk = 0; kk < 16; ++kk) {
            int m = (m0 + kk * st) & 63;
            float wr = twr[m], wi = twi[m];
            accR[kk] += ar * wr;
            accI[kk] += ar * wi;
            if (CPLX) {
                accR[kk] -= ai * wi;
                accI[kk] += ai * wr;
            }
        }
    }
    long obase = (long)b * HWP * C + (long)keep * oSK + c0 + c;
    #pragma unroll
    for (int kk = 0; kk < 16; ++kk) {
        int k = kgrp + (kk << 2);
        long a = obase + (long)k * oSJ;
        outR[a] = accR[kk] * 0.125f;
        if (outI) outI[a] = accI[kk] * 0.125f;
    }
}

// ---------------- complex block-diag matmul (per-frequency), opt softshrink ----------------
template<int SHRINK>
__global__ __launch_bounds__(256) void cmatmul_kernel(
    const float* __restrict__ XR, const float* __restrict__ XI,
    const float* __restrict__ w0, const float* __restrict__ w1,
    const float* __restrict__ b0, const float* __restrict__ b1,
    float* __restrict__ OR_, float* __restrict__ OI_, int K)
{
    __shared__ float sxr[64][33];
    __shared__ float sxi[64][33];
    __shared__ float sw0[32][65];
    __shared__ float sw1[32][65];
    int bid = blockIdx.x;
    int t0 = (bid >> 2) << 6;
    int o0 = (bid & 3) << 6;
    int tid = threadIdx.x;
    int tr = tid >> 4, tc = tid & 15;
    float accr[4][4] = {}, acci[4][4] = {};
    for (int k0 = 0; k0 < K; k0 += 32) {
        __syncthreads();
        for (int it = 0; it < 8; ++it) {
            int idx = (it << 8) + tid;
            int t = idx >> 5, k = idx & 31;
            sxr[t][k] = XR[(long)(t0 + t) * K + k0 + k];
            sxi[t][k] = XI[(long)(t0 + t) * K + k0 + k];
            int kw = idx >> 6, o = idx & 63;
            sw0[kw][o] = w0[(k0 + kw) * HID + o0 + o];
            sw1[kw][o] = w1[(k0 + kw) * HID + o0 + o];
        }
        __syncthreads();
        #pragma unroll 8
        for (int k = 0; k < 32; ++k) {
            float xr4[4], xi4[4], wv0[4], wv1[4];
            #pragma unroll
            for (int i = 0; i < 4; ++i) { xr4[i] = sxr[tr * 4 + i][k]; xi4[i] = sxi[tr * 4 + i][k]; }
            #pragma unroll
            for (int j = 0; j < 4; ++j) { wv0[j] = sw0[k][tc * 4 + j]; wv1[j] = sw1[k][tc * 4 + j]; }
            #pragma unroll
            for (int i = 0; i < 4; ++i)
                #pragma unroll
                for (int j = 0; j < 4; ++j) {
                    accr[i][j] += xr4[i] * wv0[j] - xi4[i] * wv1[j];
                    acci[i][j] += xi4[i] * wv0[j] + xr4[i] * wv1[j];
                }
        }
    }
    float bv0[4], bv1[4];
    #pragma unroll
    for (int j = 0; j < 4; ++j) { bv0[j] = b0[o0 + tc * 4 + j]; bv1[j] = b1[o0 + tc * 4 + j]; }
    #pragma unroll
    for (int i = 0; i < 4; ++i) {
        float orr[4], oii[4];
        #pragma unroll
        for (int j = 0; j < 4; ++j) {
            float r = accr[i][j] + bv0[j];
            float im = acci[i][j] + bv1[j];
            if (SHRINK) { r = sshrink(r); im = sshrink(im); }
            orr[j] = r; oii[j] = im;
        }
        *(float4*)&OR_[(long)(t0 + tr * 4 + i) * HID + o0 + tc * 4] = make_float4(orr[0], orr[1], orr[2], orr[3]);
        *(float4*)&OI_[(long)(t0 + tr * 4 + i) * HID + o0 + tc * 4] = make_float4(oii[0], oii[1], oii[2], oii[3]);
    }
}

// ---------------- frequency modulation + channel softmax (in-place on x) ----------------
__global__ __launch_bounds__(256) void mod_kernel(
    float* __restrict__ xr_, float* __restrict__ xi_,
    const float* __restrict__ pr_, const float* __restrict__ pi_,
    const float* __restrict__ alpha)
{
    int p = blockIdx.x, c = threadIdx.x;
    long idx = (long)p * HID + c;
    float xr = xr_[idx], xi = xi_[idx];
    float pr = pr_[idx], pi = pi_[idx];
    float al = alpha[c];
    float mo = sqrtf(xr * xr + xi * xi);
    float mp = sqrtf(pr * pr + pi * pi);
    float cx, sx, cp, sp;
    if (mo > 0.f) { float r = 1.f / mo; cx = xr * r; sx = xi * r; } else { cx = 1.f; sx = 0.f; }
    if (mp > 0.f) { float r = 1.f / mp; cp = pr * r; sp = pi * r; } else { cp = 1.f; sp = 0.f; }
    float sc = al * cx + (1.f - al) * cp;
    float ssn = al * sx + (1.f - al) * sp;
    float nrm = sqrtf(sc * sc + ssn * ssn + 1e-8f);
    float oc = sc / nrm, os = ssn / nrm;
    float cross = pr * xr + pi * xi;
    float sim = cross / (mp * mo + 1e-8f);
    __shared__ float red[4];
    float mv = sim;
    #pragma unroll
    for (int off = 1; off < 64; off <<= 1) mv = fmaxf(mv, __shfl_xor(mv, off));
    int wid = c >> 6;
    if ((c & 63) == 0) red[wid] = mv;
    __syncthreads();
    mv = fmaxf(fmaxf(red[0], red[1]), fmaxf(red[2], red[3]));
    float e = expf(sim - mv);
    float sum = e;
    #pragma unroll
    for (int off = 1; off < 64; off <<= 1) sum += __shfl_xor(sum, off);
    __syncthreads();
    if ((c & 63) == 0) red[wid] = sum;
    __syncthreads();
    sum = red[0] + red[1] + red[2] + red[3];
    float soft = e / sum;
    float mag = mo * soft;
    xr_[idx] = fmaxf(mag * oc, 0.f);
    xi_[idx] = fmaxf(mag * os, 0.f);
}

// ---------------- elementwise add ----------------
__global__ __launch_bounds__(256) void add_kernel(const float* __restrict__ a,
    const float* __restrict__ b, float* __restrict__ o, int n4)
{
    int i = blockIdx.x * 256 + threadIdx.x;
    if (i < n4) {
        float4 x = ((const float4*)a)[i];
        float4 y = ((const float4*)b)[i];
        ((float4*)o)[i] = make_float4(x.x + y.x, x.y + y.y, x.z + y.z, x.w + y.w);
    }
}

// ---------------- LN2 over 256 channels ----------------
__global__ __launch_bounds__(256) void ln2_kernel(const float* __restrict__ h,
    const float* __restrict__ g, const float* __restrict__ be, float* __restrict__ m)
{
    int t = blockIdx.x, c = threadIdx.x;
    float v = h[(long)t * HID + c];
    float s = v, ss = v * v;
    #pragma unroll
    for (int off = 1; off < 64; off <<= 1) { s += __shfl_xor(s, off); ss += __shfl_xor(ss, off); }
    __shared__ float r1[4], r2[4];
    int wid = c >> 6;
    if ((c & 63) == 0) { r1[wid] = s; r2[wid] = ss; }
    __syncthreads();
    s = r1[0] + r1[1] + r1[2] + r1[3];
    ss = r2[0] + r2[1] + r2[2] + r2[3];
    float mu = s * (1.f / HID);
    float var = ss * (1.f / HID) - mu * mu;
    float rstd = rsqrtf(var + 1e-5f);
    m[(long)t * HID + c] = (v - mu) * rstd * g[c] + be[c];
}

// ---------------- MLP fc1 + exact gelu -> bf16 hidden ----------------
__global__ __launch_bounds__(256) void mlp1_kernel(const float* __restrict__ M,
    const float* __restrict__ w, const float* __restrict__ bias, u16* __restrict__ hid)
{
    __shared__ float sm[64][33];
    __shared__ float swt[64][33];
    int bid = blockIdx.x;
    int t0 = (bid >> 5) << 6;
    int o0 = (bid & 31) << 6;
    int tid = threadIdx.x;
    int tr = tid >> 4, tc = tid & 15;
    float acc[4][4] = {};
    for (int k0 = 0; k0 < HID; k0 += 32) {
        __syncthreads();
        for (int it = 0; it < 8; ++it) {
            int idx = (it << 8) + tid;
            int t = idx >> 5, k = idx & 31;
            sm[t][k] = M[(long)(t0 + t) * HID + k0 + k];
            swt[t][k] = w[(long)(o0 + t) * HID + k0 + k];
        }
        __syncthreads();
        #pragma unroll 8
        for (int k = 0; k < 32; ++k) {
            float a[4], wv[4];
            #pragma unroll
            for (int i = 0; i < 4; ++i) a[i] = sm[tr * 4 + i][k];
            #pragma unroll
            for (int j = 0; j < 4; ++j) wv[j] = swt[tc * 4 + j][k];
            #pragma unroll
            for (int i = 0; i < 4; ++i)
                #pragma unroll
                for (int j = 0; j < 4; ++j) acc[i][j] += a[i] * wv[j];
        }
    }
    float bv[4];
    #pragma unroll
    for (int j = 0; j < 4; ++j) bv[j] = bias[o0 + tc * 4 + j];
    #pragma unroll
    for (int i = 0; i < 4; ++i) {
        ushort4 u;
        float v0 = acc[i][0] + bv[0], v1 = acc[i][1] + bv[1];
        float v2 = acc[i][2] + bv[2], v3 = acc[i][3] + bv[3];
        u.x = f2bf(0.5f * v0 * (1.f + erff(v0 * 0.70710678118654752440f)));
        u.y = f2bf(0.5f * v1 * (1.f + erff(v1 * 0.70710678118654752440f)));
        u.z = f2bf(0.5f * v2 * (1.f + erff(v2 * 0.70710678118654752440f)));
        u.w = f2bf(0.5f * v3 * (1.f + erff(v3 * 0.70710678118654752440f)));
        *(ushort4*)&hid[(long)(t0 + tr * 4 + i) * MLPH + o0 + tc * 4] = u;
    }
}

// ---------------- MLP fc2 + bias + h, transposed write to (B,C,H,W) ----------------
__global__ __launch_bounds__(256) void mlp2_kernel(const u16* __restrict__ hid,
    const float* __restrict__ w, const float* __restrict__ bias,
    const float* __restrict__ hbuf, float* __restrict__ out)
{
    __shared__ float smem[64 * 33 * 2];
    float* sh = smem;
    float* sw_ = smem + 64 * 33;
    int bid = blockIdx.x;
    int t0 = (bid >> 2) << 6;
    int o0 = (bid & 3) << 6;
    int tid = threadIdx.x;
    int tr = tid >> 4, tc = tid & 15;
    float acc[4][4] = {};
    for (int k0 = 0; k0 < MLPH; k0 += 32) {
        __syncthreads();
        for (int it = 0; it < 8; ++it) {
            int idx = (it << 8) + tid;
            int t = idx >> 5, k = idx & 31;
            sh[t * 33 + k] = bf2f(hid[(long)(t0 + t) * MLPH + k0 + k]);
            sw_[t * 33 + k] = w[(long)(o0 + t) * MLPH + k0 + k];
        }
        __syncthreads();
        #pragma unroll 8
        for (int k = 0; k < 32; ++k) {
            float a[4], wv[4];
            #pragma unroll
            for (int i = 0; i < 4; ++i) a[i] = sh[(tr * 4 + i) * 33 + k];
            #pragma unroll
            for (int j = 0; j < 4; ++j) wv[j] = sw_[(tc * 4 + j) * 33 + k];
            #pragma unroll
            for (int i = 0; i < 4; ++i)
                #pragma unroll
                for (int j = 0; j < 4; ++j) acc[i][j] += a[i] * wv[j];
        }
    }
    __syncthreads();
    #pragma unroll
    for (int i = 0; i < 4; ++i)
        #pragma unroll
        for (int j = 0; j < 4; ++j) {
            float v = acc[i][j] + bias[o0 + tc * 4 + j]
                    + hbuf[(long)(t0 + tr * 4 + i) * HID + o0 + tc * 4 + j];
            smem[(tc * 4 + j) * 65 + tr * 4 + i] = v;
        }
    __syncthreads();
    int b = t0 >> 12;
    int s0 = t0 & 4095;
    for (int it = 0; it < 16; ++it) {
        int idx = (it << 8) + tid;
        int ol = idx >> 6, tl = idx & 63;
        out[(long)(b * HID + o0 + ol) * HWP + s0 + tl] = smem[ol * 65 + tl];
    }
}

extern "C" void kernel_launch(void* const* d_in, const int* in_sizes, int n_in,
                              void* d_out, int out_size, void* d_ws, size_t ws_size,
                              hipStream_t stream)
{
    (void)in_sizes; (void)n_in; (void)out_size; (void)ws_size;
    const float* x     = (const float*)d_in[0];
    const float* xp    = (const float*)d_in[1];
    const float* w1    = (const float*)d_in[3];
    const float* b1    = (const float*)d_in[4];
    const float* w2    = (const float*)d_in[5];
    const float* b2    = (const float*)d_in[6];
    const float* w3    = (const float*)d_in[7];
    const float* b3    = (const float*)d_in[8];
    const float* alpha = (const float*)d_in[9];
    const float* g1    = (const float*)d_in[10];
    const float* be1   = (const float*)d_in[11];
    const float* g2    = (const float*)d_in[12];
    const float* be2   = (const float*)d_in[13];
    const float* pw    = (const float*)d_in[14];
    const float* pb    = (const float*)d_in[15];
    const float* fc1w  = (const float*)d_in[16];
    const float* fc1b  = (const float*)d_in[17];
    const float* fc2w  = (const float*)d_in[18];
    const float* fc2b  = (const float*)d_in[19];
    float* out = (float*)d_out;

    float* ws = (float*)d_ws;
    float* S0 = ws + 0 * SLOTF;
    float* S1 = ws + 1 * SLOTF;
    float* S2 = ws + 2 * SLOTF;
    float* S3 = ws + 3 * SLOTF;
    float* S4 = ws + 4 * SLOTF;
    float* S5 = ws + 5 * SLOTF;
    float* S6 = ws + 6 * SLOTF;

    float* RES = S0;
    float* XN  = S1;                       // 16MB (B*T*128)
    float* Ar  = S2; float* Ai = S2 + SLOTF / 2;
    float* Br  = S1; float* Bi = S1 + SLOTF / 2;   // after XN consumed
    float* X1r = S2; float* X1i = S3;      // after A consumed
    float* P1r = S4; float* P1i = S5;
    float* P2r = S1; float* P2i = S6;      // after B consumed
    float* P3r = S4; float* P3i = S5;      // after P1 consumed
    float* O2r = S4; float* O2i = S5;      // after P3 consumed (mod in-place on X1)
    float* Sr2 = S1; float* Si2 = S6;      // after P2 consumed
    float* Y   = S2;                       // after O1 consumed
    float* Hb  = S6;                       // after Si2 consumed
    float* Mb  = S5;                       // after O2i consumed
    u16*   HIDB = (u16*)S0;                // 128MB spanning S0..S3 (all dead)

    dim3 blk(256);

    // 1. LN1 and residual projection
    ln1_kernel<<<512, blk, 0, stream>>>(x, g1, be1, XN);
    resid_kernel<<<2048, blk, 0, stream>>>(x, pw, pb, RES);
    // 2-3. forward FFT2 of xn (W then H), ortho (0.125 per stage)
    dft64_kernel<false><<<1024, blk, 0, stream>>>(XN, nullptr, Ar, Ai,
        128, 524288L, 8192L, 1L, 128L, 8192L, 128L, -1.f);
    dft64_kernel<true><<<1024, blk, 0, stream>>>(Ar, Ai, Br, Bi,
        128, 524288L, 128L, 1L, 8192L, 128L, 8192L, -1.f);
    // 4. cmatmul w1 : 128 -> 256
    cmatmul_kernel<0><<<2048, blk, 0, stream>>>(Br, Bi, w1, w1 + 128 * 256,
        b1, b1 + 256, X1r, X1i, 128);
    // 5-6. forward FFT2 of x_pangu ((B,C,H,W) input, transpose folded into stage 1)
    dft64_kernel<false><<<2048, blk, 0, stream>>>(xp, nullptr, P1r, P1i,
        256, 1048576L, 64L, 4096L, 1L, 16384L, 256L, -1.f);
    dft64_kernel<true><<<2048, blk, 0, stream>>>(P1r, P1i, P2r, P2i,
        256, 1048576L, 256L, 1L, 16384L, 256L, 16384L, -1.f);
    // 7. cmatmul w3 : 256 -> 256
    cmatmul_kernel<0><<<2048, blk, 0, stream>>>(P2r, P2i, w3, w3 + 256 * 256,
        b3, b3 + 256, P3r, P3i, 256);
    // 8. phase-guided modulation + channel softmax (in-place on X1)
    mod_kernel<<<32768, blk, 0, stream>>>(X1r, X1i, P3r, P3i, alpha);
    // 9. cmatmul w2 + softshrink
    cmatmul_kernel<1><<<2048, blk, 0, stream>>>(X1r, X1i, w2, w2 + 256 * 256,
        b2, b2 + 256, O2r, O2i, 256);
    // 10-11. inverse FFT2 (H then W), real output only
    dft64_kernel<true><<<2048, blk, 0, stream>>>(O2r, O2i, Sr2, Si2,
        256, 1048576L, 256L, 1L, 16384L, 256L, 16384L, 1.f);
    dft64_kernel<true><<<2048, blk, 0, stream>>>(Sr2, Si2, Y, nullptr,
        256, 1048576L, 16384L, 1L, 256L, 16384L, 256L, 1.f);
    // 12. h = f + residual
    add_kernel<<<8192, blk, 0, stream>>>(Y, RES, Hb, NTOK * HID / 4);
    // 13. LN2
    ln2_kernel<<<32768, blk, 0, stream>>>(Hb, g2, be2, Mb);
    // 14-15. MLP (fc1 + exact gelu -> bf16 hidden; fc2 + bias + h, transposed out)
    mlp1_kernel<<<16384, blk, 0, stream>>>(Mb, fc1w, fc1b, HIDB);
    mlp2_kernel<<<2048, blk, 0, stream>>>(HIDB, fc2w, fc2b, Hb, out);
}

// Round 2
// 1596.202 us; speedup vs baseline: 1.8281x; 1.8281x over previous
//
#include <hip/hip_runtime.h>
#include <hip/hip_bf16.h>
#include <math.h>

#define NBATCH 8
#define HWP 4096
#define NTOK 32768
#define CIN 128
#define HID 256
#define MLPH 2048
#define SLOTF 8388608L   // floats per 32MB slot

typedef unsigned short u16;
typedef __attribute__((ext_vector_type(8))) short bf16x8;
typedef __attribute__((ext_vector_type(4))) float f32x4;
typedef __attribute__((ext_vector_type(8))) unsigned short ushort8_t;

__device__ __forceinline__ float bf2f(u16 v) { return __uint_as_float(((unsigned)v) << 16); }
__device__ __forceinline__ u16 f2bf(float f) {
    unsigned u = __float_as_uint(f);
    u = u + 0x7fffu + ((u >> 16) & 1u);
    return (u16)(u >> 16);
}
__device__ __forceinline__ float sshrink(float v) {
    return v > 0.01f ? v - 0.01f : (v < -0.01f ? v + 0.01f : 0.f);
}

// ---------------- LN1: x (B,128,4096) -> xn (B*4096,128) ----------------
__global__ __launch_bounds__(256) void ln1_kernel(const float* __restrict__ x,
    const float* __restrict__ g, const float* __restrict__ be, float* __restrict__ xn)
{
    __shared__ float xt[CIN][65];
    __shared__ float mu_s[64], rs_s[64];
    int bid = blockIdx.x;
    int b = bid >> 6;
    int t0 = (bid & 63) << 6;
    int tid = threadIdx.x;
    for (int it = 0; it < 32; ++it) {
        int idx = (it << 8) + tid;
        int c = idx >> 6, t = idx & 63;
        xt[c][t] = x[(long)(b * CIN + c) * HWP + t0 + t];
    }
    __syncthreads();
    int tt = tid >> 2, p = tid & 3;
    float s = 0.f, ss = 0.f;
    #pragma unroll
    for (int i = 0; i < 32; ++i) {
        float v = xt[p * 32 + i][tt];
        s += v; ss += v * v;
    }
    s += __shfl_xor(s, 1); ss += __shfl_xor(ss, 1);
    s += __shfl_xor(s, 2); ss += __shfl_xor(ss, 2);
    if (p == 0) {
        float mu = s * (1.f / CIN);
        float var = ss * (1.f / CIN) - mu * mu;
        mu_s[tt] = mu;
        rs_s[tt] = rsqrtf(var + 1e-5f);
    }
    __syncthreads();
    for (int it = 0; it < 32; ++it) {
        int idx = (it << 8) + tid;
        int t = idx >> 7, c = idx & 127;
        xn[((long)b * HWP + t0 + t) * CIN + c] = (xt[c][t] - mu_s[t]) * rs_s[t] * g[c] + be[c];
    }
}

// ---------------- residual GEMM: tok(B,T,128) @ proj_w(256,128)^T ----------------
__global__ __launch_bounds__(256) void resid_kernel(const float* __restrict__ x,
    const float* __restrict__ pw, const float* __restrict__ pb, float* __restrict__ res)
{
    __shared__ float xt[64][65];
    __shared__ float wt[64][65];
    int bid = blockIdx.x;
    int t0g = (bid >> 2) << 6;
    int o0 = (bid & 3) << 6;
    int b = t0g >> 12;
    int t0 = t0g & 4095;
    int tid = threadIdx.x;
    int tr = tid >> 4, tc = tid & 15;
    float acc[4][4] = {};
    for (int k0 = 0; k0 < CIN; k0 += 64) {
        __syncthreads();
        for (int it = 0; it < 16; ++it) {
            int idx = (it << 8) + tid;
            int r = idx >> 6, cc = idx & 63;
            xt[r][cc] = x[(long)(b * CIN + k0 + r) * HWP + t0 + cc];
            wt[r][cc] = pw[(o0 + r) * CIN + k0 + cc];
        }
        __syncthreads();
        #pragma unroll 8
        for (int k = 0; k < 64; ++k) {
            float a[4], w[4];
            #pragma unroll
            for (int i = 0; i < 4; ++i) a[i] = xt[k][tr * 4 + i];
            #pragma unroll
            for (int j = 0; j < 4; ++j) w[j] = wt[tc * 4 + j][k];
            #pragma unroll
            for (int i = 0; i < 4; ++i)
                #pragma unroll
                for (int j = 0; j < 4; ++j) acc[i][j] += a[i] * w[j];
        }
    }
    float pbv[4];
    #pragma unroll
    for (int j = 0; j < 4; ++j) pbv[j] = pb[o0 + tc * 4 + j];
    #pragma unroll
    for (int i = 0; i < 4; ++i) {
        float4 v = make_float4(acc[i][0] + pbv[0], acc[i][1] + pbv[1],
                               acc[i][2] + pbv[2], acc[i][3] + pbv[3]);
        *(float4*)&res[(long)(t0g + tr * 4 + i) * HID + o0 + tc * 4] = v;
    }
}

// ---------------- generic 64-point DFT along one axis ----------------
template<bool CPLX>
__global__ __launch_bounds__(256) void dft64_kernel(
    const float* __restrict__ inR, const float* __restrict__ inI,
    float* __restrict__ outR, float* __restrict__ outI,
    int C, long inSB, long inSK, long inSC, long inSJ,
    long oSK, long oSJ, float sgn)
{
    __shared__ float lr[64][64];
    __shared__ float li[64][64];
    __shared__ float twr[64], twi[64];
    int cb = C >> 6;
    int bid = blockIdx.x;
    int b = bid / (64 * cb);
    int rem = bid % (64 * cb);
    int keep = rem / cb;
    int c0 = (rem % cb) << 6;
    int tid = threadIdx.x;
    if (tid < 64) {
        float sv, cv;
        sincosf(6.283185307179586f * (float)tid / 64.f, &sv, &cv);
        twr[tid] = cv; twi[tid] = sgn * sv;
    }
    long base = (long)b * inSB + (long)keep * inSK + (long)c0 * inSC;
    for (int it = 0; it < 16; ++it) {
        int idx = (it << 8) + tid;
        int j, c;
        if (inSJ == 1) { j = idx & 63; c = idx >> 6; }
        else           { c = idx & 63; j = idx >> 6; }
        long a = base + (long)c * inSC + (long)j * inSJ;
        lr[j][c] = inR[a];
        if (CPLX) li[j][c] = inI[a];
    }
    __syncthreads();
    int c = tid & 63;
    int kgrp = tid >> 6;
    float accR[16], accI[16];
    #pragma unroll
    for (int kk = 0; kk < 16; ++kk) { accR[kk] = 0.f; accI[kk] = 0.f; }
    for (int j = 0; j < 64; ++j) {
        float ar = lr[j][c];
        float ai = CPLX ? li[j][c] : 0.f;
        int m0 = (j * kgrp) & 63;
        int st = (j << 2) & 63;
        #pragma unroll
        for (int kk = 0; kk < 16; ++kk) {
            int m = (m0 + kk * st) & 63;
            float wr = twr[m], wi = twi[m];
            accR[kk] += ar * wr;
            accI[kk] += ar * wi;
            if (CPLX) {
                accR[kk] -= ai * wi;
                accI[kk] += ai * wr;
            }
        }
    }
    long obase = (long)b * HWP * C + (long)keep * oSK + c0 + c;
    #pragma unroll
    for (int kk = 0; kk < 16; ++kk) {
        int k = kgrp + (kk << 2);
        long a = obase + (long)k * oSJ;
        outR[a] = accR[kk] * 0.125f;
        if (outI) outI[a] = accI[kk] * 0.125f;
    }
}

// ---------------- complex block-diag matmul (per-frequency), opt softshrink ----------------
template<int SHRINK>
__global__ __launch_bounds__(256) void cmatmul_kernel(
    const float* __restrict__ XR, const float* __restrict__ XI,
    const float* __restrict__ w0, const float* __restrict__ w1,
    const float* __restrict__ b0, const float* __restrict__ b1,
    float* __restrict__ OR_, float* __restrict__ OI_, int K)
{
    __shared__ float sxr[64][33];
    __shared__ float sxi[64][33];
    __shared__ float sw0[32][65];
    __shared__ float sw1[32][65];
    int bid = blockIdx.x;
    int t0 = (bid >> 2) << 6;
    int o0 = (bid & 3) << 6;
    int tid = threadIdx.x;
    int tr = tid >> 4, tc = tid & 15;
    float accr[4][4] = {}, acci[4][4] = {};
    for (int k0 = 0; k0 < K; k0 += 32) {
        __syncthreads();
        for (int it = 0; it < 8; ++it) {
            int idx = (it << 8) + tid;
            int t = idx >> 5, k = idx & 31;
            sxr[t][k] = XR[(long)(t0 + t) * K + k0 + k];
            sxi[t][k] = XI[(long)(t0 + t) * K + k0 + k];
            int kw = idx >> 6, o = idx & 63;
            sw0[kw][o] = w0[(k0 + kw) * HID + o0 + o];
            sw1[kw][o] = w1[(k0 + kw) * HID + o0 + o];
        }
        __syncthreads();
        #pragma unroll 8
        for (int k = 0; k < 32; ++k) {
            float xr4[4], xi4[4], wv0[4], wv1[4];
            #pragma unroll
            for (int i = 0; i < 4; ++i) { xr4[i] = sxr[tr * 4 + i][k]; xi4[i] = sxi[tr * 4 + i][k]; }
            #pragma unroll
            for (int j = 0; j < 4; ++j) { wv0[j] = sw0[k][tc * 4 + j]; wv1[j] = sw1[k][tc * 4 + j]; }
            #pragma unroll
            for (int i = 0; i < 4; ++i)
                #pragma unroll
                for (int j = 0; j < 4; ++j) {
                    accr[i][j] += xr4[i] * wv0[j] - xi4[i] * wv1[j];
                    acci[i][j] += xi4[i] * wv0[j] + xr4[i] * wv1[j];
                }
        }
    }
    float bv0[4], bv1[4];
    #pragma unroll
    for (int j = 0; j < 4; ++j) { bv0[j] = b0[o0 + tc * 4 + j]; bv1[j] = b1[o0 + tc * 4 + j]; }
    #pragma unroll
    for (int i = 0; i < 4; ++i) {
        float orr[4], oii[4];
        #pragma unroll
        for (int j = 0; j < 4; ++j) {
            float r = accr[i][j] + bv0[j];
            float im = acci[i][j] + bv1[j];
            if (SHRINK) { r = sshrink(r); im = sshrink(im); }
            orr[j] = r; oii[j] = im;
        }
        *(float4*)&OR_[(long)(t0 + tr * 4 + i) * HID + o0 + tc * 4] = make_float4(orr[0], orr[1], orr[2], orr[3]);
        *(float4*)&OI_[(long)(t0 + tr * 4 + i) * HID + o0 + tc * 4] = make_float4(oii[0], oii[1], oii[2], oii[3]);
    }
}

// ---------------- frequency modulation + channel softmax (in-place on x) ----------------
__global__ __launch_bounds__(256) void mod_kernel(
    float* __restrict__ xr_, float* __restrict__ xi_,
    const float* __restrict__ pr_, const float* __restrict__ pi_,
    const float* __restrict__ alpha)
{
    int p = blockIdx.x, c = threadIdx.x;
    long idx = (long)p * HID + c;
    float xr = xr_[idx], xi = xi_[idx];
    float pr = pr_[idx], pi = pi_[idx];
    float al = alpha[c];
    float mo = sqrtf(xr * xr + xi * xi);
    float mp = sqrtf(pr * pr + pi * pi);
    float cx, sx, cp, sp;
    if (mo > 0.f) { float r = 1.f / mo; cx = xr * r; sx = xi * r; } else { cx = 1.f; sx = 0.f; }
    if (mp > 0.f) { float r = 1.f / mp; cp = pr * r; sp = pi * r; } else { cp = 1.f; sp = 0.f; }
    float sc = al * cx + (1.f - al) * cp;
    float ssn = al * sx + (1.f - al) * sp;
    float nrm = sqrtf(sc * sc + ssn * ssn + 1e-8f);
    float oc = sc / nrm, os = ssn / nrm;
    float cross = pr * xr + pi * xi;
    float sim = cross / (mp * mo + 1e-8f);
    __shared__ float red[4];
    float mv = sim;
    #pragma unroll
    for (int off = 1; off < 64; off <<= 1) mv = fmaxf(mv, __shfl_xor(mv, off));
    int wid = c >> 6;
    if ((c & 63) == 0) red[wid] = mv;
    __syncthreads();
    mv = fmaxf(fmaxf(red[0], red[1]), fmaxf(red[2], red[3]));
    float e = expf(sim - mv);
    float sum = e;
    #pragma unroll
    for (int off = 1; off < 64; off <<= 1) sum += __shfl_xor(sum, off);
    __syncthreads();
    if ((c & 63) == 0) red[wid] = sum;
    __syncthreads();
    sum = red[0] + red[1] + red[2] + red[3];
    float soft = e / sum;
    float mag = mo * soft;
    xr_[idx] = fmaxf(mag * oc, 0.f);
    xi_[idx] = fmaxf(mag * os, 0.f);
}

// ---------------- elementwise add ----------------
__global__ __launch_bounds__(256) void add_kernel(const float* __restrict__ a,
    const float* __restrict__ b, float* __restrict__ o, int n4)
{
    int i = blockIdx.x * 256 + threadIdx.x;
    if (i < n4) {
        float4 x = ((const float4*)a)[i];
        float4 y = ((const float4*)b)[i];
        ((float4*)o)[i] = make_float4(x.x + y.x, x.y + y.y, x.z + y.z, x.w + y.w);
    }
}

// ---------------- LN2 over 256 channels -> bf16 out ----------------
__global__ __launch_bounds__(256) void ln2_kernel(const float* __restrict__ h,
    const float* __restrict__ g, const float* __restrict__ be, u16* __restrict__ m)
{
    int t = blockIdx.x, c = threadIdx.x;
    float v = h[(long)t * HID + c];
    float s = v, ss = v * v;
    #pragma unroll
    for (int off = 1; off < 64; off <<= 1) { s += __shfl_xor(s, off); ss += __shfl_xor(ss, off); }
    __shared__ float r1[4], r2[4];
    int wid = c >> 6;
    if ((c & 63) == 0) { r1[wid] = s; r2[wid] = ss; }
    __syncthreads();
    s = r1[0] + r1[1] + r1[2] + r1[3];
    ss = r2[0] + r2[1] + r2[2] + r2[3];
    float mu = s * (1.f / HID);
    float var = ss * (1.f / HID) - mu * mu;
    float rstd = rsqrtf(var + 1e-5f);
    m[(long)t * HID + c] = f2bf((v - mu) * rstd * g[c] + be[c]);
}

// ---------------- fp32 -> bf16 convert ----------------
__global__ __launch_bounds__(256) void f2bf_kernel(const float* __restrict__ in,
    u16* __restrict__ out, int n)
{
    int i = (blockIdx.x * 256 + threadIdx.x) * 4;
    if (i < n) {
        float4 v = *(const float4*)&in[i];
        ushort4 o;
        o.x = f2bf(v.x); o.y = f2bf(v.y); o.z = f2bf(v.z); o.w = f2bf(v.w);
        *(ushort4*)&out[i] = o;
    }
}

// ---------------- MFMA bf16 GEMM: C = A(M,K) x Bw(N,K)^T ----------------
// EPI 0: out = bf16 gelu(C + bias)          (mlp1 -> hidden)
// EPI 1: out(B,C,H,W) = C + bias + hbuf     (mlp2, transposed store)
template<int EPI>
__global__ __launch_bounds__(256) void gemm_mfma_kernel(
    const u16* __restrict__ A, const u16* __restrict__ Bw,
    const float* __restrict__ bias, const float* __restrict__ hbuf,
    void* __restrict__ outp, int M, int N, int K)
{
    __shared__ __align__(16) char smem[EPI ? (128 * 132 * 4) : (128 * 136 * 2)];
    u16* ldsA = (u16*)smem;            // [128][64]
    u16* ldsB = (u16*)(smem + 16384);  // [128][64]
    int tid = threadIdx.x;
    int nbn = N >> 7;
    int bRow = (int)(blockIdx.x / nbn) << 7;
    int bCol = (int)(blockIdx.x % nbn) << 7;
    int lane = tid & 63;
    int w = tid >> 6;
    int wr = (w >> 1) << 6;
    int wc = (w & 1) << 6;
    int ln15 = lane & 15;
    int kg = lane >> 4;

    f32x4 acc[4][4] = {};

    int srow = tid >> 3;
    int skc = (tid & 7) << 3;
    const u16* gA = A + (long)(bRow + srow) * K + skc;
    const u16* gB = Bw + (long)(bCol + srow) * K + skc;
    u16* lA = ldsA + srow * 64 + skc;
    u16* lB = ldsB + srow * 64 + skc;

    for (int k0 = 0; k0 < K; k0 += 64) {
        __syncthreads();
        #pragma unroll
        for (int c = 0; c < 4; ++c) {
            __builtin_amdgcn_global_load_lds(
                (const __attribute__((address_space(1))) void*)(gA + (long)c * 32 * K + k0),
                (__attribute__((address_space(3))) void*)(lA + c * 32 * 64), 16, 0, 0);
            __builtin_amdgcn_global_load_lds(
                (const __attribute__((address_space(1))) void*)(gB + (long)c * 32 * K + k0),
                (__attribute__((address_space(3))) void*)(lB + c * 32 * 64), 16, 0, 0);
        }
        __syncthreads();
        #pragma unroll
        for (int kk = 0; kk < 64; kk += 32) {
            bf16x8 av[4], bv[4];
            #pragma unroll
            for (int m = 0; m < 4; ++m)
                av[m] = *(const bf16x8*)(ldsA + (wr + m * 16 + ln15) * 64 + kk + kg * 8);
            #pragma unroll
            for (int n = 0; n < 4; ++n)
                bv[n] = *(const bf16x8*)(ldsB + (wc + n * 16 + ln15) * 64 + kk + kg * 8);
            #pragma unroll
            for (int m = 0; m < 4; ++m)
                #pragma unroll
                for (int n = 0; n < 4; ++n)
                    acc[m][n] = __builtin_amdgcn_mfma_f32_16x16x32_bf16(av[m], bv[n], acc[m][n], 0, 0, 0);
        }
    }
    __syncthreads();

    if (EPI == 0) {
        u16* lds2 = (u16*)smem;  // [128][136]
        float bn[4];
        #pragma unroll
        for (int n = 0; n < 4; ++n) bn[n] = bias[bCol + wc + n * 16 + ln15];
        #pragma unroll
        for (int m = 0; m < 4; ++m)
            #pragma unroll
            for (int n = 0; n < 4; ++n) {
                int col = wc + n * 16 + ln15;
                #pragma unroll
                for (int r = 0; r < 4; ++r) {
                    int row = wr + m * 16 + kg * 4 + r;
                    float v = acc[m][n][r] + bn[n];
                    float gv = 0.5f * v * (1.f + erff(v * 0.70710678118654752440f));
                    lds2[row * 136 + col] = f2bf(gv);
                }
            }
        __syncthreads();
        u16* O = (u16*)outp;
        #pragma unroll
        for (int it = 0; it < 8; ++it) {
            int idx = (it << 8) + tid;
            int row = idx >> 4, c8 = (idx & 15) << 3;
            *(ushort8_t*)&O[(long)(bRow + row) * N + bCol + c8] = *(const ushort8_t*)&lds2[row * 136 + c8];
        }
    } else {
        float* ldsf = (float*)smem;  // [128 cols][132]
        float bn[4];
        #pragma unroll
        for (int n = 0; n < 4; ++n) bn[n] = bias[bCol + wc + n * 16 + ln15];
        #pragma unroll
        for (int m = 0; m < 4; ++m)
            #pragma unroll
            for (int n = 0; n < 4; ++n) {
                int col = wc + n * 16 + ln15;
                #pragma unroll
                for (int r = 0; r < 4; ++r) {
                    int row = wr + m * 16 + kg * 4 + r;
                    float v = acc[m][n][r] + bn[n] + hbuf[(long)(bRow + row) * HID + bCol + col];
                    ldsf[col * 132 + row] = v;
                }
            }
        __syncthreads();
        float* O = (float*)outp;
        int b = bRow >> 12;
        int s0 = bRow & 4095;
        #pragma unroll
        for (int it = 0; it < 16; ++it) {
            int idx = (it << 8) + tid;
            int oc = idx >> 5, r4 = (idx & 31) << 2;
            *(float4*)&O[((long)(b * HID + bCol + oc)) * HWP + s0 + r4] = *(const float4*)&ldsf[oc * 132 + r4];
        }
    }
}

extern "C" void kernel_launch(void* const* d_in, const int* in_sizes, int n_in,
                              void* d_out, int out_size, void* d_ws, size_t ws_size,
                              hipStream_t stream)
{
    (void)in_sizes; (void)n_in; (void)out_size; (void)ws_size;
    const float* x     = (const float*)d_in[0];
    const float* xp    = (const float*)d_in[1];
    const float* w1    = (const float*)d_in[3];
    const float* b1    = (const float*)d_in[4];
    const float* w2    = (const float*)d_in[5];
    const float* b2    = (const float*)d_in[6];
    const float* w3    = (const float*)d_in[7];
    const float* b3    = (const float*)d_in[8];
    const float* alpha = (const float*)d_in[9];
    const float* g1    = (const float*)d_in[10];
    const float* be1   = (const float*)d_in[11];
    const float* g2    = (const float*)d_in[12];
    const float* be2   = (const float*)d_in[13];
    const float* pw    = (const float*)d_in[14];
    const float* pb    = (const float*)d_in[15];
    const float* fc1w  = (const float*)d_in[16];
    const float* fc1b  = (const float*)d_in[17];
    const float* fc2w  = (const float*)d_in[18];
    const float* fc2b  = (const float*)d_in[19];
    float* out = (float*)d_out;

    float* ws = (float*)d_ws;
    float* S0 = ws + 0 * SLOTF;
    float* S1 = ws + 1 * SLOTF;
    float* S2 = ws + 2 * SLOTF;
    float* S3 = ws + 3 * SLOTF;
    float* S4 = ws + 4 * SLOTF;
    float* S5 = ws + 5 * SLOTF;
    float* S6 = ws + 6 * SLOTF;

    float* RES = S0;
    float* XN  = S1;
    float* Ar  = S2; float* Ai = S2 + SLOTF / 2;
    float* Br  = S1; float* Bi = S1 + SLOTF / 2;
    float* X1r = S2; float* X1i = S3;
    float* P1r = S4; float* P1i = S5;
    float* P2r = S1; float* P2i = S6;
    float* P3r = S4; float* P3i = S5;
    float* O2r = S4; float* O2i = S5;
    float* Sr2 = S1; float* Si2 = S6;
    float* Y   = S2;
    float* Hb  = S6;
    u16*   Mb16 = (u16*)S5;
    u16*   WB1 = (u16*)S4;                 // S4 dead after iFFT stage 1
    u16*   WB2 = (u16*)S4 + 524288;
    u16*   HIDB = (u16*)S0;                // 128 MiB spanning S0..S3

    dim3 blk(256);

    // 1. LN1 and residual projection
    ln1_kernel<<<512, blk, 0, stream>>>(x, g1, be1, XN);
    resid_kernel<<<2048, blk, 0, stream>>>(x, pw, pb, RES);
    // 2-3. forward FFT2 of xn (W then H)
    dft64_kernel<false><<<1024, blk, 0, stream>>>(XN, nullptr, Ar, Ai,
        128, 524288L, 8192L, 1L, 128L, 8192L, 128L, -1.f);
    dft64_kernel<true><<<1024, blk, 0, stream>>>(Ar, Ai, Br, Bi,
        128, 524288L, 128L, 1L, 8192L, 128L, 8192L, -1.f);
    // 4. cmatmul w1 : 128 -> 256
    cmatmul_kernel<0><<<2048, blk, 0, stream>>>(Br, Bi, w1, w1 + 128 * 256,
        b1, b1 + 256, X1r, X1i, 128);
    // 5-6. forward FFT2 of x_pangu
    dft64_kernel<false><<<2048, blk, 0, stream>>>(xp, nullptr, P1r, P1i,
        256, 1048576L, 64L, 4096L, 1L, 16384L, 256L, -1.f);
    dft64_kernel<true><<<2048, blk, 0, stream>>>(P1r, P1i, P2r, P2i,
        256, 1048576L, 256L, 1L, 16384L, 256L, 16384L, -1.f);
    // 7. cmatmul w3 : 256 -> 256
    cmatmul_kernel<0><<<2048, blk, 0, stream>>>(P2r, P2i, w3, w3 + 256 * 256,
        b3, b3 + 256, P3r, P3i, 256);
    // 8. modulation + channel softmax (in-place on X1)
    mod_kernel<<<32768, blk, 0, stream>>>(X1r, X1i, P3r, P3i, alpha);
    // 9. cmatmul w2 + softshrink
    cmatmul_kernel<1><<<2048, blk, 0, stream>>>(X1r, X1i, w2, w2 + 256 * 256,
        b2, b2 + 256, O2r, O2i, 256);
    // 10-11. inverse FFT2
    dft64_kernel<true><<<2048, blk, 0, stream>>>(O2r, O2i, Sr2, Si2,
        256, 1048576L, 256L, 1L, 16384L, 256L, 16384L, 1.f);
    dft64_kernel<true><<<2048, blk, 0, stream>>>(Sr2, Si2, Y, nullptr,
        256, 1048576L, 16384L, 1L, 256L, 16384L, 256L, 1.f);
    // 12. h = f + residual
    add_kernel<<<8192, blk, 0, stream>>>(Y, RES, Hb, NTOK * HID / 4);
    // 13. LN2 -> bf16
    ln2_kernel<<<32768, blk, 0, stream>>>(Hb, g2, be2, Mb16);
    // 13b. weight conversion to bf16
    f2bf_kernel<<<512, blk, 0, stream>>>(fc1w, WB1, MLPH * HID);
    f2bf_kernel<<<512, blk, 0, stream>>>(fc2w, WB2, HID * MLPH);
    // 14. MLP fc1 (MFMA) + gelu -> bf16 hidden
    gemm_mfma_kernel<0><<<4096, blk, 0, stream>>>(Mb16, WB1, fc1b, nullptr,
        (void*)HIDB, NTOK, MLPH, HID);
    // 15. MLP fc2 (MFMA) + bias + h, transposed out
    gemm_mfma_kernel<1><<<512, blk, 0, stream>>>(HIDB, WB2, fc2b, Hb,
        (void*)out, NTOK, HID, MLPH);
}

// Round 3
// 888.067 us; speedup vs baseline: 3.2857x; 1.7974x over previous
//
#include <hip/hip_runtime.h>
#include <hip/hip_bf16.h>
#include <math.h>

#define NBATCH 8
#define HWP 4096
#define NTOK 32768
#define CIN 128
#define HID 256
#define MLPH 2048
#define SLOTF 8388608L   // floats per 32MB slot

typedef unsigned short u16;
typedef __attribute__((ext_vector_type(8))) short bf16x8;
typedef __attribute__((ext_vector_type(4))) float f32x4;
typedef __attribute__((ext_vector_type(8))) unsigned short ushort8_t;

__device__ __forceinline__ float bf2f(u16 v) { return __uint_as_float(((unsigned)v) << 16); }
__device__ __forceinline__ u16 f2bf(float f) {
    unsigned u = __float_as_uint(f);
    u = u + 0x7fffu + ((u >> 16) & 1u);
    return (u16)(u >> 16);
}
__device__ __forceinline__ float sshrink(float v) {
    return v > 0.01f ? v - 0.01f : (v < -0.01f ? v + 0.01f : 0.f);
}

// ---------------- LN1: x (B,128,4096) -> xn (B*4096,128) ----------------
__global__ __launch_bounds__(256) void ln1_kernel(const float* __restrict__ x,
    const float* __restrict__ g, const float* __restrict__ be, float* __restrict__ xn)
{
    __shared__ float xt[CIN][65];
    __shared__ float mu_s[64], rs_s[64];
    int bid = blockIdx.x;
    int b = bid >> 6;
    int t0 = (bid & 63) << 6;
    int tid = threadIdx.x;
    for (int it = 0; it < 32; ++it) {
        int idx = (it << 8) + tid;
        int c = idx >> 6, t = idx & 63;
        xt[c][t] = x[(long)(b * CIN + c) * HWP + t0 + t];
    }
    __syncthreads();
    int tt = tid >> 2, p = tid & 3;
    float s = 0.f, ss = 0.f;
    #pragma unroll
    for (int i = 0; i < 32; ++i) {
        float v = xt[p * 32 + i][tt];
        s += v; ss += v * v;
    }
    s += __shfl_xor(s, 1); ss += __shfl_xor(ss, 1);
    s += __shfl_xor(s, 2); ss += __shfl_xor(ss, 2);
    if (p == 0) {
        float mu = s * (1.f / CIN);
        float var = ss * (1.f / CIN) - mu * mu;
        mu_s[tt] = mu;
        rs_s[tt] = rsqrtf(var + 1e-5f);
    }
    __syncthreads();
    for (int it = 0; it < 32; ++it) {
        int idx = (it << 8) + tid;
        int t = idx >> 7, c = idx & 127;
        xn[((long)b * HWP + t0 + t) * CIN + c] = (xt[c][t] - mu_s[t]) * rs_s[t] * g[c] + be[c];
    }
}

// ---------------- residual GEMM: tok(B,T,128) @ proj_w(256,128)^T ----------------
__global__ __launch_bounds__(256) void resid_kernel(const float* __restrict__ x,
    const float* __restrict__ pw, const float* __restrict__ pb, float* __restrict__ res)
{
    __shared__ float xt[64][65];
    __shared__ float wt[64][65];
    int bid = blockIdx.x;
    int t0g = (bid >> 2) << 6;
    int o0 = (bid & 3) << 6;
    int b = t0g >> 12;
    int t0 = t0g & 4095;
    int tid = threadIdx.x;
    int tr = tid >> 4, tc = tid & 15;
    float acc[4][4] = {};
    for (int k0 = 0; k0 < CIN; k0 += 64) {
        __syncthreads();
        for (int it = 0; it < 16; ++it) {
            int idx = (it << 8) + tid;
            int r = idx >> 6, cc = idx & 63;
            xt[r][cc] = x[(long)(b * CIN + k0 + r) * HWP + t0 + cc];
            wt[r][cc] = pw[(o0 + r) * CIN + k0 + cc];
        }
        __syncthreads();
        #pragma unroll 8
        for (int k = 0; k < 64; ++k) {
            float a[4], w[4];
            #pragma unroll
            for (int i = 0; i < 4; ++i) a[i] = xt[k][tr * 4 + i];
            #pragma unroll
            for (int j = 0; j < 4; ++j) w[j] = wt[tc * 4 + j][k];
            #pragma unroll
            for (int i = 0; i < 4; ++i)
                #pragma unroll
                for (int j = 0; j < 4; ++j) acc[i][j] += a[i] * w[j];
        }
    }
    float pbv[4];
    #pragma unroll
    for (int j = 0; j < 4; ++j) pbv[j] = pb[o0 + tc * 4 + j];
    #pragma unroll
    for (int i = 0; i < 4; ++i) {
        float4 v = make_float4(acc[i][0] + pbv[0], acc[i][1] + pbv[1],
                               acc[i][2] + pbv[2], acc[i][3] + pbv[3]);
        *(float4*)&res[(long)(t0g + tr * 4 + i) * HID + o0 + tc * 4] = v;
    }
}

// ---------------- generic 64-point DFT along one axis ----------------
// in addr = b*inSB + keep*inSK + c*inSC + j*inSJ
// out fp32: a = b*oSB + keep*oSK + k*oSJ + c0 + c  (+ optional addend fusion)
// out bf16 packed (BFOUT=1): u16 at a (real), a + C (imag)
template<bool CPLX, int BFOUT>
__global__ __launch_bounds__(256) void dft64_kernel(
    const float* __restrict__ inR, const float* __restrict__ inI,
    void* __restrict__ outR, float* __restrict__ outI,
    const float* __restrict__ addend,
    int C, long inSB, long inSK, long inSC, long inSJ,
    long oSB, long oSK, long oSJ, float sgn)
{
    __shared__ float lr[64][64];
    __shared__ float li[64][64];
    __shared__ float twr[64], twi[64];
    int cb = C >> 6;
    int bid = blockIdx.x;
    int b = bid / (64 * cb);
    int rem = bid % (64 * cb);
    int keep = rem / cb;
    int c0 = (rem % cb) << 6;
    int tid = threadIdx.x;
    if (tid < 64) {
        float sv, cv;
        sincosf(6.283185307179586f * (float)tid / 64.f, &sv, &cv);
        twr[tid] = cv; twi[tid] = sgn * sv;
    }
    long base = (long)b * inSB + (long)keep * inSK + (long)c0 * inSC;
    for (int it = 0; it < 16; ++it) {
        int idx = (it << 8) + tid;
        int j, c;
        if (inSJ == 1) { j = idx & 63; c = idx >> 6; }
        else           { c = idx & 63; j = idx >> 6; }
        long a = base + (long)c * inSC + (long)j * inSJ;
        lr[j][c] = inR[a];
        if (CPLX) li[j][c] = inI[a];
    }
    __syncthreads();
    int c = tid & 63;
    int kgrp = tid >> 6;
    float accR[16], accI[16];
    #pragma unroll
    for (int kk = 0; kk < 16; ++kk) { accR[kk] = 0.f; accI[kk] = 0.f; }
    for (int j = 0; j < 64; ++j) {
        float ar = lr[j][c];
        float ai = CPLX ? li[j][c] : 0.f;
        int m0 = (j * kgrp) & 63;
        int st = (j << 2) & 63;
        #pragma unroll
        for (int kk = 0; kk < 16; ++kk) {
            int m = (m0 + kk * st) & 63;
            float wr = twr[m], wi = twi[m];
            accR[kk] += ar * wr;
            accI[kk] += ar * wi;
            if (CPLX) {
                accR[kk] -= ai * wi;
                accI[kk] += ai * wr;
            }
        }
    }
    long obase = (long)b * oSB + (long)keep * oSK + c0 + c;
    if (BFOUT) {
        u16* o16 = (u16*)outR;
        #pragma unroll
        for (int kk = 0; kk < 16; ++kk) {
            int k = kgrp + (kk << 2);
            long a = obase + (long)k * oSJ;
            o16[a] = f2bf(accR[kk] * 0.125f);
            o16[a + C] = f2bf(accI[kk] * 0.125f);
        }
    } else {
        float* oR = (float*)outR;
        #pragma unroll
        for (int kk = 0; kk < 16; ++kk) {
            int k = kgrp + (kk << 2);
            long a = obase + (long)k * oSJ;
            float v = accR[kk] * 0.125f;
            if (addend) v += addend[a];
            oR[a] = v;
            if (outI) outI[a] = accI[kk] * 0.125f;
        }
    }
}

// ---------------- complex weight repack: w(2,K,256) -> Bw(512, 2K) bf16 ----------------
__global__ __launch_bounds__(256) void wcvt_kernel(const float* __restrict__ w,
    int K, u16* __restrict__ out)
{
    int idx = blockIdx.x * 256 + threadIdx.x;   // k*256 + o
    int k = idx >> 8, o = idx & 255;
    float w0 = w[k * 256 + o];
    float w1v = w[K * 256 + k * 256 + o];
    long K2 = 2L * K;
    out[(long)o * K2 + k] = f2bf(w0);
    out[(long)o * K2 + K + k] = f2bf(-w1v);
    out[(long)(256 + o) * K2 + k] = f2bf(w1v);
    out[(long)(256 + o) * K2 + K + k] = f2bf(w0);
}

// ---------------- frequency modulation + channel softmax (bf16 packed) ----------------
__global__ __launch_bounds__(256) void mod_kernel(
    const u16* __restrict__ x1, const u16* __restrict__ p3,
    const float* __restrict__ alpha, u16* __restrict__ a2)
{
    int p = blockIdx.x, c = threadIdx.x;
    long base = (long)p * 512;
    float xr = bf2f(x1[base + c]), xi = bf2f(x1[base + 256 + c]);
    float pr = bf2f(p3[base + c]), pi = bf2f(p3[base + 256 + c]);
    float al = alpha[c];
    float mo = sqrtf(xr * xr + xi * xi);
    float mp = sqrtf(pr * pr + pi * pi);
    float cx, sx, cp, sp;
    if (mo > 0.f) { float r = 1.f / mo; cx = xr * r; sx = xi * r; } else { cx = 1.f; sx = 0.f; }
    if (mp > 0.f) { float r = 1.f / mp; cp = pr * r; sp = pi * r; } else { cp = 1.f; sp = 0.f; }
    float sc = al * cx + (1.f - al) * cp;
    float ssn = al * sx + (1.f - al) * sp;
    float nrm = sqrtf(sc * sc + ssn * ssn + 1e-8f);
    float oc = sc / nrm, os = ssn / nrm;
    float cross = pr * xr + pi * xi;
    float sim = cross / (mp * mo + 1e-8f);
    __shared__ float red[4];
    float mv = sim;
    #pragma unroll
    for (int off = 1; off < 64; off <<= 1) mv = fmaxf(mv, __shfl_xor(mv, off));
    int wid = c >> 6;
    if ((c & 63) == 0) red[wid] = mv;
    __syncthreads();
    mv = fmaxf(fmaxf(red[0], red[1]), fmaxf(red[2], red[3]));
    float e = expf(sim - mv);
    float sum = e;
    #pragma unroll
    for (int off = 1; off < 64; off <<= 1) sum += __shfl_xor(sum, off);
    __syncthreads();
    if ((c & 63) == 0) red[wid] = sum;
    __syncthreads();
    sum = red[0] + red[1] + red[2] + red[3];
    float soft = e / sum;
    float mag = mo * soft;
    a2[base + c] = f2bf(fmaxf(mag * oc, 0.f));
    a2[base + 256 + c] = f2bf(fmaxf(mag * os, 0.f));
}

// ---------------- LN2 over 256 channels -> bf16 out ----------------
__global__ __launch_bounds__(256) void ln2_kernel(const float* __restrict__ h,
    const float* __restrict__ g, const float* __restrict__ be, u16* __restrict__ m)
{
    int t = blockIdx.x, c = threadIdx.x;
    float v = h[(long)t * HID + c];
    float s = v, ss = v * v;
    #pragma unroll
    for (int off = 1; off < 64; off <<= 1) { s += __shfl_xor(s, off); ss += __shfl_xor(ss, off); }
    __shared__ float r1[4], r2[4];
    int wid = c >> 6;
    if ((c & 63) == 0) { r1[wid] = s; r2[wid] = ss; }
    __syncthreads();
    s = r1[0] + r1[1] + r1[2] + r1[3];
    ss = r2[0] + r2[1] + r2[2] + r2[3];
    float mu = s * (1.f / HID);
    float var = ss * (1.f / HID) - mu * mu;
    float rstd = rsqrtf(var + 1e-5f);
    m[(long)t * HID + c] = f2bf((v - mu) * rstd * g[c] + be[c]);
}

// ---------------- fp32 -> bf16 convert ----------------
__global__ __launch_bounds__(256) void f2bf_kernel(const float* __restrict__ in,
    u16* __restrict__ out, int n)
{
    int i = (blockIdx.x * 256 + threadIdx.x) * 4;
    if (i < n) {
        float4 v = *(const float4*)&in[i];
        ushort4 o;
        o.x = f2bf(v.x); o.y = f2bf(v.y); o.z = f2bf(v.z); o.w = f2bf(v.w);
        *(ushort4*)&out[i] = o;
    }
}

// ---------------- MFMA bf16 GEMM: C = A(M,K) x Bw(N,K)^T ----------------
// EPI 0: bf16 out = gelu(C + bias)
// EPI 1: fp32 out(B,C,H,W) = C + bias + hbuf (transposed store)
// EPI 2: bf16 out = C + bias
// EPI 3: fp32 out = softshrink(C + bias)
template<int EPI>
__global__ __launch_bounds__(256) void gemm_mfma_kernel(
    const u16* __restrict__ A, const u16* __restrict__ Bw,
    const float* __restrict__ bias, const float* __restrict__ hbuf,
    void* __restrict__ outp, int M, int N, int K)
{
    __shared__ __align__(16) char smem[(EPI == 1 || EPI == 3) ? (128 * 132 * 4) : (128 * 136 * 2)];
    u16* ldsA = (u16*)smem;            // [128][64]
    u16* ldsB = (u16*)(smem + 16384);  // [128][64]
    int tid = threadIdx.x;
    int nbn = N >> 7;
    int bRow = (int)(blockIdx.x / nbn) << 7;
    int bCol = (int)(blockIdx.x % nbn) << 7;
    int lane = tid & 63;
    int w = tid >> 6;
    int wr = (w >> 1) << 6;
    int wc = (w & 1) << 6;
    int ln15 = lane & 15;
    int kg = lane >> 4;

    f32x4 acc[4][4] = {};

    int srow = tid >> 3;
    int skc = (tid & 7) << 3;
    const u16* gA = A + (long)(bRow + srow) * K + skc;
    const u16* gB = Bw + (long)(bCol + srow) * K + skc;
    u16* lA = ldsA + srow * 64 + skc;
    u16* lB = ldsB + srow * 64 + skc;

    for (int k0 = 0; k0 < K; k0 += 64) {
        __syncthreads();
        #pragma unroll
        for (int c = 0; c < 4; ++c) {
            __builtin_amdgcn_global_load_lds(
                (const __attribute__((address_space(1))) void*)(gA + (long)c * 32 * K + k0),
                (__attribute__((address_space(3))) void*)(lA + c * 32 * 64), 16, 0, 0);
            __builtin_amdgcn_global_load_lds(
                (const __attribute__((address_space(1))) void*)(gB + (long)c * 32 * K + k0),
                (__attribute__((address_space(3))) void*)(lB + c * 32 * 64), 16, 0, 0);
        }
        __syncthreads();
        #pragma unroll
        for (int kk = 0; kk < 64; kk += 32) {
            bf16x8 av[4], bv[4];
            #pragma unroll
            for (int m = 0; m < 4; ++m)
                av[m] = *(const bf16x8*)(ldsA + (wr + m * 16 + ln15) * 64 + kk + kg * 8);
            #pragma unroll
            for (int n = 0; n < 4; ++n)
                bv[n] = *(const bf16x8*)(ldsB + (wc + n * 16 + ln15) * 64 + kk + kg * 8);
            #pragma unroll
            for (int m = 0; m < 4; ++m)
                #pragma unroll
                for (int n = 0; n < 4; ++n)
                    acc[m][n] = __builtin_amdgcn_mfma_f32_16x16x32_bf16(av[m], bv[n], acc[m][n], 0, 0, 0);
        }
    }
    __syncthreads();

    if (EPI == 0 || EPI == 2) {
        u16* lds2 = (u16*)smem;  // [128][136]
        float bn[4];
        #pragma unroll
        for (int n = 0; n < 4; ++n) bn[n] = bias[bCol + wc + n * 16 + ln15];
        #pragma unroll
        for (int m = 0; m < 4; ++m)
            #pragma unroll
            for (int n = 0; n < 4; ++n) {
                int col = wc + n * 16 + ln15;
                #pragma unroll
                for (int r = 0; r < 4; ++r) {
                    int row = wr + m * 16 + kg * 4 + r;
                    float v = acc[m][n][r] + bn[n];
                    if (EPI == 0) v = 0.5f * v * (1.f + erff(v * 0.70710678118654752440f));
                    lds2[row * 136 + col] = f2bf(v);
                }
            }
        __syncthreads();
        u16* O = (u16*)outp;
        #pragma unroll
        for (int it = 0; it < 8; ++it) {
            int idx = (it << 8) + tid;
            int row = idx >> 4, c8 = (idx & 15) << 3;
            *(ushort8_t*)&O[(long)(bRow + row) * N + bCol + c8] = *(const ushort8_t*)&lds2[row * 136 + c8];
        }
    } else if (EPI == 3) {
        float* ldsf = (float*)smem;  // [128][132]
        float bn[4];
        #pragma unroll
        for (int n = 0; n < 4; ++n) bn[n] = bias[bCol + wc + n * 16 + ln15];
        #pragma unroll
        for (int m = 0; m < 4; ++m)
            #pragma unroll
            for (int n = 0; n < 4; ++n) {
                int col = wc + n * 16 + ln15;
                #pragma unroll
                for (int r = 0; r < 4; ++r) {
                    int row = wr + m * 16 + kg * 4 + r;
                    ldsf[row * 132 + col] = sshrink(acc[m][n][r] + bn[n]);
                }
            }
        __syncthreads();
        float* O = (float*)outp;
        #pragma unroll
        for (int it = 0; it < 16; ++it) {
            int idx = (it << 8) + tid;
            int row = idx >> 5, c4 = (idx & 31) << 2;
            *(float4*)&O[(long)(bRow + row) * N + bCol + c4] = *(const float4*)&ldsf[row * 132 + c4];
        }
    } else {  // EPI 1
        float* ldsf = (float*)smem;  // [128 cols][132]
        float bn[4];
        #pragma unroll
        for (int n = 0; n < 4; ++n) bn[n] = bias[bCol + wc + n * 16 + ln15];
        #pragma unroll
        for (int m = 0; m < 4; ++m)
            #pragma unroll
            for (int n = 0; n < 4; ++n) {
                int col = wc + n * 16 + ln15;
                #pragma unroll
                for (int r = 0; r < 4; ++r) {
                    int row = wr + m * 16 + kg * 4 + r;
                    float v = acc[m][n][r] + bn[n] + hbuf[(long)(bRow + row) * HID + bCol + col];
                    ldsf[col * 132 + row] = v;
                }
            }
        __syncthreads();
        float* O = (float*)outp;
        int b = bRow >> 12;
        int s0 = bRow & 4095;
        #pragma unroll
        for (int it = 0; it < 16; ++it) {
            int idx = (it << 8) + tid;
            int oc = idx >> 5, r4 = (idx & 31) << 2;
            *(float4*)&O[((long)(b * HID + bCol + oc)) * HWP + s0 + r4] = *(const float4*)&ldsf[oc * 132 + r4];
        }
    }
}

extern "C" void kernel_launch(void* const* d_in, const int* in_sizes, int n_in,
                              void* d_out, int out_size, void* d_ws, size_t ws_size,
                              hipStream_t stream)
{
    (void)in_sizes; (void)n_in; (void)out_size; (void)ws_size;
    const float* x     = (const float*)d_in[0];
    const float* xp    = (const float*)d_in[1];
    const float* w1    = (const float*)d_in[3];
    const float* b1    = (const float*)d_in[4];
    const float* w2    = (const float*)d_in[5];
    const float* b2    = (const float*)d_in[6];
    const float* w3    = (const float*)d_in[7];
    const float* b3    = (const float*)d_in[8];
    const float* alpha = (const float*)d_in[9];
    const float* g1    = (const float*)d_in[10];
    const float* be1   = (const float*)d_in[11];
    const float* g2    = (const float*)d_in[12];
    const float* be2   = (const float*)d_in[13];
    const float* pw    = (const float*)d_in[14];
    const float* pb    = (const float*)d_in[15];
    const float* fc1w  = (const float*)d_in[16];
    const float* fc1b  = (const float*)d_in[17];
    const float* fc2w  = (const float*)d_in[18];
    const float* fc2b  = (const float*)d_in[19];
    float* out = (float*)d_out;

    float* ws = (float*)d_ws;
    float* S0 = ws + 0 * SLOTF;
    float* S1 = ws + 1 * SLOTF;
    float* S2 = ws + 2 * SLOTF;
    float* S3 = ws + 3 * SLOTF;
    float* S4 = ws + 4 * SLOTF;
    float* S5 = ws + 5 * SLOTF;
    float* S6 = ws + 6 * SLOTF;

    float* RES  = S0;                     // fp32 32MB, live ->add
    float* XN   = S1;                     // fp32 16MB
    float* Ar   = S2; float* Ai = S3;     // fp32 16MB each
    u16*   XF   = (u16*)S1;               // bf16 [32768][256] 16MB
    u16*   W1c  = (u16*)S3;               // bf16 512x256, 256KB
    u16*   X1   = (u16*)S2;               // bf16 [32768][512] 32MB
    float* P1r  = S1; float* P1i = S3;    // fp32 32MB each
    u16*   PF   = (u16*)S4;               // bf16 [32768][512] 32MB
    u16*   W3c  = (u16*)S3;               // bf16 512x512, 512KB
    u16*   P3   = (u16*)S5;               // bf16 [32768][512] 32MB
    u16*   W2c  = (u16*)S4;               // bf16 512x512, 512KB
    u16*   A2   = (u16*)S6;               // bf16 [32768][512] 32MB
    float* O2   = S2;                     // fp32 [32768][512] 64MB (S2+S3)
    float* Sr2  = S1; float* Si2 = S4;    // fp32 32MB each
    float* Hb   = S6;                     // fp32 32MB (iFFT s2 fused +RES writes here)
    u16*   Mb16 = (u16*)S5;               // bf16 16MB
    u16*   WB1  = (u16*)S5 + SLOTF;       // bf16 1MB (S5 bytes 16MB+)
    u16*   WB2  = (u16*)S5 + SLOTF + 524288;
    u16*   HIDB = (u16*)S0;               // bf16 128MB spanning S0..S3

    dim3 blk(256);

    // 1. LN1 and residual projection
    ln1_kernel<<<512, blk, 0, stream>>>(x, g1, be1, XN);
    resid_kernel<<<2048, blk, 0, stream>>>(x, pw, pb, RES);
    // 2-3. forward FFT2 of xn (W then H) -> packed bf16 [Xr|Xi]
    dft64_kernel<false, 0><<<1024, blk, 0, stream>>>(XN, nullptr, Ar, Ai, nullptr,
        128, 524288L, 8192L, 1L, 128L, 524288L, 8192L, 128L, -1.f);
    dft64_kernel<true, 1><<<1024, blk, 0, stream>>>(Ar, Ai, XF, nullptr, nullptr,
        128, 524288L, 128L, 1L, 8192L, 1048576L, 256L, 16384L, -1.f);
    // 4. complex GEMM w1 (K=2*128): X1 = [Or|Oi] bf16
    wcvt_kernel<<<128, blk, 0, stream>>>(w1, 128, W1c);
    gemm_mfma_kernel<2><<<1024, blk, 0, stream>>>(XF, W1c, b1, nullptr,
        (void*)X1, NTOK, 512, 256);
    // 5-6. forward FFT2 of x_pangu -> packed bf16
    dft64_kernel<false, 0><<<2048, blk, 0, stream>>>(xp, nullptr, P1r, P1i, nullptr,
        256, 1048576L, 64L, 4096L, 1L, 1048576L, 16384L, 256L, -1.f);
    dft64_kernel<true, 1><<<2048, blk, 0, stream>>>(P1r, P1i, PF, nullptr, nullptr,
        256, 1048576L, 256L, 1L, 16384L, 2097152L, 512L, 32768L, -1.f);
    // 7. complex GEMM w3 (K=2*256): P3 bf16
    wcvt_kernel<<<256, blk, 0, stream>>>(w3, 256, W3c);
    gemm_mfma_kernel<2><<<1024, blk, 0, stream>>>(PF, W3c, b3, nullptr,
        (void*)P3, NTOK, 512, 512);
    // 8. modulation + channel softmax -> A2 bf16
    wcvt_kernel<<<256, blk, 0, stream>>>(w2, 256, W2c);
    mod_kernel<<<32768, blk, 0, stream>>>(X1, P3, alpha, A2);
    // 9. complex GEMM w2 + softshrink -> O2 fp32 packed
    gemm_mfma_kernel<3><<<1024, blk, 0, stream>>>(A2, W2c, b2, nullptr,
        (void*)O2, NTOK, 512, 512);
    // 10-11. inverse FFT2 (H then W); stage 2 fuses + RES -> Hb
    dft64_kernel<true, 0><<<2048, blk, 0, stream>>>(O2, O2 + 256, Sr2, Si2, nullptr,
        256, 2097152L, 512L, 1L, 32768L, 1048576L, 256L, 16384L, 1.f);
    dft64_kernel<true, 0><<<2048, blk, 0, stream>>>(Sr2, Si2, Hb, nullptr, RES,
        256, 1048576L, 16384L, 1L, 256L, 1048576L, 16384L, 256L, 1.f);
    // 12. weight conversion for MLP (S5 tail free after Y-slot died)
    f2bf_kernel<<<512, blk, 0, stream>>>(fc1w, WB1, MLPH * HID);
    f2bf_kernel<<<512, blk, 0, stream>>>(fc2w, WB2, HID * MLPH);
    // 13. LN2 -> bf16
    ln2_kernel<<<32768, blk, 0, stream>>>(Hb, g2, be2, Mb16);
    // 14. MLP fc1 (MFMA) + gelu -> bf16 hidden
    gemm_mfma_kernel<0><<<4096, blk, 0, stream>>>(Mb16, WB1, fc1b, nullptr,
        (void*)HIDB, NTOK, MLPH, HID);
    // 15. MLP fc2 (MFMA) + bias + h, transposed out
    gemm_mfma_kernel<1><<<512, blk, 0, stream>>>(HIDB, WB2, fc2b, Hb,
        (void*)out, NTOK, HID, MLPH);
}

// Round 4
// 531.260 us; speedup vs baseline: 5.4925x; 1.6716x over previous
//
#include <hip/hip_runtime.h>
#include <hip/hip_bf16.h>
#include <math.h>

#define NBATCH 8
#define HWP 4096
#define NTOK 32768
#define CIN 128
#define HID 256
#define MLPH 2048
#define SLOTF 8388608L   // floats per 32MB slot

typedef unsigned short u16;
typedef __attribute__((ext_vector_type(8))) short bf16x8;
typedef __attribute__((ext_vector_type(4))) float f32x4;
typedef __attribute__((ext_vector_type(8))) unsigned short ushort8_t;
typedef __attribute__((ext_vector_type(2))) unsigned long long u64x2;

__device__ __forceinline__ float bf2f(u16 v) { return __uint_as_float(((unsigned)v) << 16); }
__device__ __forceinline__ u16 f2bf(float f) {
    unsigned u = __float_as_uint(f);
    u = u + 0x7fffu + ((u >> 16) & 1u);
    return (u16)(u >> 16);
}
__device__ __forceinline__ u16 bits2bf(unsigned u) {
    u = u + 0x7fffu + ((u >> 16) & 1u);
    return (u16)(u >> 16);
}
__device__ __forceinline__ float sshrink(float v) {
    return v > 0.01f ? v - 0.01f : (v < -0.01f ? v + 0.01f : 0.f);
}

// ---------------- LN1: x (B,128,4096) -> xn (B*4096,128) ----------------
__global__ __launch_bounds__(256) void ln1_kernel(const float* __restrict__ x,
    const float* __restrict__ g, const float* __restrict__ be, float* __restrict__ xn)
{
    __shared__ float xt[CIN][65];
    __shared__ float mu_s[64], rs_s[64];
    int bid = blockIdx.x;
    int b = bid >> 6;
    int t0 = (bid & 63) << 6;
    int tid = threadIdx.x;
    for (int it = 0; it < 32; ++it) {
        int idx = (it << 8) + tid;
        int c = idx >> 6, t = idx & 63;
        xt[c][t] = x[(long)(b * CIN + c) * HWP + t0 + t];
    }
    __syncthreads();
    int tt = tid >> 2, p = tid & 3;
    float s = 0.f, ss = 0.f;
    #pragma unroll
    for (int i = 0; i < 32; ++i) {
        float v = xt[p * 32 + i][tt];
        s += v; ss += v * v;
    }
    s += __shfl_xor(s, 1); ss += __shfl_xor(ss, 1);
    s += __shfl_xor(s, 2); ss += __shfl_xor(ss, 2);
    if (p == 0) {
        float mu = s * (1.f / CIN);
        float var = ss * (1.f / CIN) - mu * mu;
        mu_s[tt] = mu;
        rs_s[tt] = rsqrtf(var + 1e-5f);
    }
    __syncthreads();
    for (int it = 0; it < 32; ++it) {
        int idx = (it << 8) + tid;
        int t = idx >> 7, c = idx & 127;
        xn[((long)b * HWP + t0 + t) * CIN + c] = (xt[c][t] - mu_s[t]) * rs_s[t] * g[c] + be[c];
    }
}

// ---------------- residual GEMM: tok(B,T,128) @ proj_w(256,128)^T ----------------
__global__ __launch_bounds__(256) void resid_kernel(const float* __restrict__ x,
    const float* __restrict__ pw, const float* __restrict__ pb, float* __restrict__ res)
{
    __shared__ float xt[64][65];
    __shared__ float wt[64][65];
    int bid = blockIdx.x;
    int t0g = (bid >> 2) << 6;
    int o0 = (bid & 3) << 6;
    int b = t0g >> 12;
    int t0 = t0g & 4095;
    int tid = threadIdx.x;
    int tr = tid >> 4, tc = tid & 15;
    float acc[4][4] = {};
    for (int k0 = 0; k0 < CIN; k0 += 64) {
        __syncthreads();
        for (int it = 0; it < 16; ++it) {
            int idx = (it << 8) + tid;
            int r = idx >> 6, cc = idx & 63;
            xt[r][cc] = x[(long)(b * CIN + k0 + r) * HWP + t0 + cc];
            wt[r][cc] = pw[(o0 + r) * CIN + k0 + cc];
        }
        __syncthreads();
        #pragma unroll 8
        for (int k = 0; k < 64; ++k) {
            float a[4], w[4];
            #pragma unroll
            for (int i = 0; i < 4; ++i) a[i] = xt[k][tr * 4 + i];
            #pragma unroll
            for (int j = 0; j < 4; ++j) w[j] = wt[tc * 4 + j][k];
            #pragma unroll
            for (int i = 0; i < 4; ++i)
                #pragma unroll
                for (int j = 0; j < 4; ++j) acc[i][j] += a[i] * w[j];
        }
    }
    float pbv[4];
    #pragma unroll
    for (int j = 0; j < 4; ++j) pbv[j] = pb[o0 + tc * 4 + j];
    #pragma unroll
    for (int i = 0; i < 4; ++i) {
        float4 v = make_float4(acc[i][0] + pbv[0], acc[i][1] + pbv[1],
                               acc[i][2] + pbv[2], acc[i][3] + pbv[3]);
        *(float4*)&res[(long)(t0g + tr * 4 + i) * HID + o0 + tc * 4] = v;
    }
}

// ---------------- twiddle tables: fwd/inv, hi/lo split, [n=128][k=128], x0.125 ----------------
__global__ __launch_bounds__(256) void tables_kernel(u16* __restrict__ tw)
{
    int idx = blockIdx.x * 256 + threadIdx.x;   // n*128 + kcol
    int n = idx >> 7, kcol = idx & 127;
    int j = kcol & 63, p = kcol >> 6;           // p: 0=re-in col, 1=im-in col
    int np = n & 63, q = n >> 6;                // q: 0=re-out, 1=im-out
    float th = 6.283185307179586f * (float)((j * np) & 63) / 64.f;
    float sv, cv;
    sincosf(th, &sv, &cv);
    // fwd sgn=-1: out_re = xr*cos + xi*sin ; out_im = -xr*sin + xi*cos
    float fw = (q == 0) ? (p == 0 ? cv : sv) : (p == 0 ? -sv : cv);
    // inv sgn=+1: out_re = xr*cos - xi*sin ; out_im = xr*sin + xi*cos
    float iv = (q == 0) ? (p == 0 ? cv : -sv) : (p == 0 ? sv : cv);
    fw *= 0.125f; iv *= 0.125f;
    u16 fh = f2bf(fw), ih = f2bf(iv);
    tw[idx] = fh;
    tw[16384 + idx] = f2bf(fw - bf2f(fh));
    tw[32768 + idx] = ih;
    tw[49152 + idx] = f2bf(iv - bf2f(ih));
}

// ---------------- MFMA 64-pt DFT along one axis ----------------
// INMODE 0: fp32 in, c-contig runs, real (K=64):  addr = ibase + j*JS + c
// INMODE 1: bf16 in, c-contig runs, cplx (K=128): addr = ibase + j*JS + p*PS + c
// INMODE 2: fp32 in, j-contig rows, real (K=64):  addr = ibase + c*JS + j
// REALOUT 0: bf16 out (c,k,p):  obase + k*KS + p*PS2 + c   (u16)
// REALOUT 1: fp32 out (c,k) + addend: obase + k*KS + c     (f32)
template<int INMODE, int REALOUT>
__global__ __launch_bounds__(256) void dftm_kernel(
    const void* __restrict__ inp, const u16* __restrict__ tw,
    void* __restrict__ outp, const float* __restrict__ addend,
    int nch, long IB, long IK, long IC, long JS, long PS,
    long OB, long OK, long OC, long KS, long PS2)
{
    constexpr int K = (INMODE == 1) ? 128 : 64;
    constexpr int AST = (K == 128) ? 136 : 72;
    constexpr int MFR = REALOUT ? 2 : 4;
    __shared__ __align__(16) u16 smem[128 * 136];
    int tid = threadIdx.x;
    int lane = tid & 63;
    int bid = blockIdx.x;
    int b = bid / (64 * nch);
    int rem = bid % (64 * nch);
    int keep = rem / nch;
    int ch = rem % nch;
    long ibase = b * IB + keep * IK + ch * IC;
    long obase = b * OB + keep * OK + ch * OC;

    if (INMODE == 0) {
        const float* inF = (const float*)inp;
        #pragma unroll
        for (int it = 0; it < 8; ++it) {
            int idx = (it << 8) + tid;
            int j = idx >> 5, c4 = (idx & 31) << 2;
            u64x2 v = *(const u64x2*)(inF + ibase + (long)j * JS + c4);
            #pragma unroll
            for (int i = 0; i < 4; ++i) {
                int vv = (i + lane) & 3;
                unsigned long long q = (vv & 2) ? v.y : v.x;
                unsigned fb = (unsigned)(q >> ((vv & 1) << 5));
                smem[(c4 + vv) * AST + j] = bits2bf(fb);
            }
        }
    } else if (INMODE == 1) {
        const u16* inU = (const u16*)inp;
        #pragma unroll
        for (int it = 0; it < 8; ++it) {
            int idx = (it << 8) + tid;
            int run = idx >> 4, c8 = (idx & 15) << 3;
            int j = run >> 1, p = run & 1;
            u64x2 v = *(const u64x2*)(inU + ibase + (long)j * JS + (long)p * PS + c8);
            int col = p * 64 + j;
            #pragma unroll
            for (int i = 0; i < 8; ++i) {
                int vv = (i + lane) & 7;
                unsigned long long q = (vv & 4) ? v.y : v.x;
                u16 val = (u16)(q >> ((vv & 3) << 4));
                smem[(c8 + vv) * AST + col] = val;
            }
        }
    } else {
        const float* inF = (const float*)inp;
        #pragma unroll
        for (int it = 0; it < 8; ++it) {
            int idx = (it << 8) + tid;
            int row = idx >> 4, j4 = (idx & 15) << 2;
            u64x2 v = *(const u64x2*)(inF + ibase + (long)row * JS + j4);
            ushort4 o;
            o.x = bits2bf((unsigned)v.x);
            o.y = bits2bf((unsigned)(v.x >> 32));
            o.z = bits2bf((unsigned)v.y);
            o.w = bits2bf((unsigned)(v.y >> 32));
            *(ushort4*)&smem[row * AST + j4] = o;
        }
    }
    __syncthreads();

    int w = tid >> 6;
    int ln15 = lane & 15, kg = lane >> 4;
    int wrow = REALOUT ? (w << 5) : ((w >> 1) << 6);
    int wcol = REALOUT ? 0 : ((w & 1) << 6);
    f32x4 acc[MFR][4] = {};
    #pragma unroll
    for (int kk = 0; kk < K / 32; ++kk) {
        bf16x8 av[MFR];
        #pragma unroll
        for (int m = 0; m < MFR; ++m)
            av[m] = *(const bf16x8*)&smem[(wrow + m * 16 + ln15) * AST + kk * 32 + kg * 8];
        #pragma unroll
        for (int n = 0; n < 4; ++n) {
            const u16* tb = tw + (wcol + n * 16 + ln15) * 128 + kk * 32 + kg * 8;
            bf16x8 bh = *(const bf16x8*)tb;
            bf16x8 bl = *(const bf16x8*)(tb + 16384);
            #pragma unroll
            for (int m = 0; m < MFR; ++m) {
                acc[m][n] = __builtin_amdgcn_mfma_f32_16x16x32_bf16(av[m], bh, acc[m][n], 0, 0, 0);
                acc[m][n] = __builtin_amdgcn_mfma_f32_16x16x32_bf16(av[m], bl, acc[m][n], 0, 0, 0);
            }
        }
    }
    __syncthreads();

    if (REALOUT == 0) {
        #pragma unroll
        for (int m = 0; m < MFR; ++m)
            #pragma unroll
            for (int n = 0; n < 4; ++n)
                #pragma unroll
                for (int r = 0; r < 4; ++r)
                    smem[(wcol + n * 16 + ln15) * 136 + wrow + m * 16 + kg * 4 + r] = f2bf(acc[m][n][r]);
        __syncthreads();
        u16* outU = (u16*)outp;
        #pragma unroll
        for (int it = 0; it < 8; ++it) {
            int idx = (it << 8) + tid;
            int n = idx >> 4, c8 = (idx & 15) << 3;
            int k = n & 63, p = n >> 6;
            *(ushort8_t*)&outU[obase + (long)k * KS + (long)p * PS2 + c8] =
                *(const ushort8_t*)&smem[n * 136 + c8];
        }
    } else {
        float* ef = (float*)smem;  // [64][132]
        #pragma unroll
        for (int m = 0; m < MFR; ++m)
            #pragma unroll
            for (int n = 0; n < 4; ++n)
                #pragma unroll
                for (int r = 0; r < 4; ++r)
                    ef[(n * 16 + ln15) * 132 + wrow + m * 16 + kg * 4 + r] = acc[m][n][r];
        __syncthreads();
        float* outF = (float*)outp;
        #pragma unroll
        for (int it = 0; it < 8; ++it) {
            int idx = (it << 8) + tid;
            int k = idx >> 5, c4 = (idx & 31) << 2;
            long a = obase + (long)k * KS + c4;
            float4 v = *(const float4*)&ef[k * 132 + c4];
            float4 rv = *(const float4*)&addend[a];
            v.x += rv.x; v.y += rv.y; v.z += rv.z; v.w += rv.w;
            *(float4*)&outF[a] = v;
        }
    }
}

// ---------------- complex weight repack: w(2,K,256) -> Bw(512, 2K) bf16 ----------------
__global__ __launch_bounds__(256) void wcvt_kernel(const float* __restrict__ w,
    int K, u16* __restrict__ out)
{
    int idx = blockIdx.x * 256 + threadIdx.x;   // k*256 + o
    int k = idx >> 8, o = idx & 255;
    float w0 = w[k * 256 + o];
    float w1v = w[K * 256 + k * 256 + o];
    long K2 = 2L * K;
    out[(long)o * K2 + k] = f2bf(w0);
    out[(long)o * K2 + K + k] = f2bf(-w1v);
    out[(long)(256 + o) * K2 + k] = f2bf(w1v);
    out[(long)(256 + o) * K2 + K + k] = f2bf(w0);
}

// ---------------- frequency modulation + channel softmax (bf16 packed) ----------------
__global__ __launch_bounds__(256) void mod_kernel(
    const u16* __restrict__ x1, const u16* __restrict__ p3,
    const float* __restrict__ alpha, u16* __restrict__ a2)
{
    int p = blockIdx.x, c = threadIdx.x;
    long base = (long)p * 512;
    float xr = bf2f(x1[base + c]), xi = bf2f(x1[base + 256 + c]);
    float pr = bf2f(p3[base + c]), pi = bf2f(p3[base + 256 + c]);
    float al = alpha[c];
    float mo = sqrtf(xr * xr + xi * xi);
    float mp = sqrtf(pr * pr + pi * pi);
    float cx, sx, cp, sp;
    if (mo > 0.f) { float r = 1.f / mo; cx = xr * r; sx = xi * r; } else { cx = 1.f; sx = 0.f; }
    if (mp > 0.f) { float r = 1.f / mp; cp = pr * r; sp = pi * r; } else { cp = 1.f; sp = 0.f; }
    float sc = al * cx + (1.f - al) * cp;
    float ssn = al * sx + (1.f - al) * sp;
    float nrm = sqrtf(sc * sc + ssn * ssn + 1e-8f);
    float oc = sc / nrm, os = ssn / nrm;
    float cross = pr * xr + pi * xi;
    float sim = cross / (mp * mo + 1e-8f);
    __shared__ float red[4];
    float mv = sim;
    #pragma unroll
    for (int off = 1; off < 64; off <<= 1) mv = fmaxf(mv, __shfl_xor(mv, off));
    int wid = c >> 6;
    if ((c & 63) == 0) red[wid] = mv;
    __syncthreads();
    mv = fmaxf(fmaxf(red[0], red[1]), fmaxf(red[2], red[3]));
    float e = expf(sim - mv);
    float sum = e;
    #pragma unroll
    for (int off = 1; off < 64; off <<= 1) sum += __shfl_xor(sum, off);
    __syncthreads();
    if ((c & 63) == 0) red[wid] = sum;
    __syncthreads();
    sum = red[0] + red[1] + red[2] + red[3];
    float soft = e / sum;
    float mag = mo * soft;
    a2[base + c] = f2bf(fmaxf(mag * oc, 0.f));
    a2[base + 256 + c] = f2bf(fmaxf(mag * os, 0.f));
}

// ---------------- LN2 over 256 channels -> bf16 out ----------------
__global__ __launch_bounds__(256) void ln2_kernel(const float* __restrict__ h,
    const float* __restrict__ g, const float* __restrict__ be, u16* __restrict__ m)
{
    int t = blockIdx.x, c = threadIdx.x;
    float v = h[(long)t * HID + c];
    float s = v, ss = v * v;
    #pragma unroll
    for (int off = 1; off < 64; off <<= 1) { s += __shfl_xor(s, off); ss += __shfl_xor(ss, off); }
    __shared__ float r1[4], r2[4];
    int wid = c >> 6;
    if ((c & 63) == 0) { r1[wid] = s; r2[wid] = ss; }
    __syncthreads();
    s = r1[0] + r1[1] + r1[2] + r1[3];
    ss = r2[0] + r2[1] + r2[2] + r2[3];
    float mu = s * (1.f / HID);
    float var = ss * (1.f / HID) - mu * mu;
    float rstd = rsqrtf(var + 1e-5f);
    m[(long)t * HID + c] = f2bf((v - mu) * rstd * g[c] + be[c]);
}

// ---------------- fp32 -> bf16 convert ----------------
__global__ __launch_bounds__(256) void f2bf_kernel(const float* __restrict__ in,
    u16* __restrict__ out, int n)
{
    int i = (blockIdx.x * 256 + threadIdx.x) * 4;
    if (i < n) {
        float4 v = *(const float4*)&in[i];
        ushort4 o;
        o.x = f2bf(v.x); o.y = f2bf(v.y); o.z = f2bf(v.z); o.w = f2bf(v.w);
        *(ushort4*)&out[i] = o;
    }
}

// ---------------- MFMA bf16 GEMM: C = A(M,K) x Bw(N,K)^T ----------------
// EPI 0: bf16 out = gelu(C + bias)
// EPI 1: fp32 out(B,C,H,W) = C + bias + hbuf (transposed store)
// EPI 2: bf16 out = C + bias
// EPI 4: bf16 out = softshrink(C + bias)
template<int EPI>
__global__ __launch_bounds__(256) void gemm_mfma_kernel(
    const u16* __restrict__ A, const u16* __restrict__ Bw,
    const float* __restrict__ bias, const float* __restrict__ hbuf,
    void* __restrict__ outp, int M, int N, int K)
{
    __shared__ __align__(16) char smem[(EPI == 1) ? (128 * 132 * 4) : (128 * 136 * 2)];
    u16* ldsA = (u16*)smem;            // [128][64]
    u16* ldsB = (u16*)(smem + 16384);  // [128][64]
    int tid = threadIdx.x;
    int nbn = N >> 7;
    int bRow = (int)(blockIdx.x / nbn) << 7;
    int bCol = (int)(blockIdx.x % nbn) << 7;
    int lane = tid & 63;
    int w = tid >> 6;
    int wr = (w >> 1) << 6;
    int wc = (w & 1) << 6;
    int ln15 = lane & 15;
    int kg = lane >> 4;

    f32x4 acc[4][4] = {};

    int srow = tid >> 3;
    int skc = (tid & 7) << 3;
    const u16* gA = A + (long)(bRow + srow) * K + skc;
    const u16* gB = Bw + (long)(bCol + srow) * K + skc;
    u16* lA = ldsA + srow * 64 + skc;
    u16* lB = ldsB + srow * 64 + skc;

    for (int k0 = 0; k0 < K; k0 += 64) {
        __syncthreads();
        #pragma unroll
        for (int c = 0; c < 4; ++c) {
            __builtin_amdgcn_global_load_lds(
                (const __attribute__((address_space(1))) void*)(gA + (long)c * 32 * K + k0),
                (__attribute__((address_space(3))) void*)(lA + c * 32 * 64), 16, 0, 0);
            __builtin_amdgcn_global_load_lds(
                (const __attribute__((address_space(1))) void*)(gB + (long)c * 32 * K + k0),
                (__attribute__((address_space(3))) void*)(lB + c * 32 * 64), 16, 0, 0);
        }
        __syncthreads();
        #pragma unroll
        for (int kk = 0; kk < 64; kk += 32) {
            bf16x8 av[4], bv[4];
            #pragma unroll
            for (int m = 0; m < 4; ++m)
                av[m] = *(const bf16x8*)(ldsA + (wr + m * 16 + ln15) * 64 + kk + kg * 8);
            #pragma unroll
            for (int n = 0; n < 4; ++n)
                bv[n] = *(const bf16x8*)(ldsB + (wc + n * 16 + ln15) * 64 + kk + kg * 8);
            #pragma unroll
            for (int m = 0; m < 4; ++m)
                #pragma unroll
                for (int n = 0; n < 4; ++n)
                    acc[m][n] = __builtin_amdgcn_mfma_f32_16x16x32_bf16(av[m], bv[n], acc[m][n], 0, 0, 0);
        }
    }
    __syncthreads();

    if (EPI == 0 || EPI == 2 || EPI == 4) {
        u16* lds2 = (u16*)smem;  // [128][136]
        float bn[4];
        #pragma unroll
        for (int n = 0; n < 4; ++n) bn[n] = bias[bCol + wc + n * 16 + ln15];
        #pragma unroll
        for (int m = 0; m < 4; ++m)
            #pragma unroll
            for (int n = 0; n < 4; ++n) {
                int col = wc + n * 16 + ln15;
                #pragma unroll
                for (int r = 0; r < 4; ++r) {
                    int row = wr + m * 16 + kg * 4 + r;
                    float v = acc[m][n][r] + bn[n];
                    if (EPI == 0) v = 0.5f * v * (1.f + erff(v * 0.70710678118654752440f));
                    if (EPI == 4) v = sshrink(v);
                    lds2[row * 136 + col] = f2bf(v);
                }
            }
        __syncthreads();
        u16* O = (u16*)outp;
        #pragma unroll
        for (int it = 0; it < 8; ++it) {
            int idx = (it << 8) + tid;
            int row = idx >> 4, c8 = (idx & 15) << 3;
            *(ushort8_t*)&O[(long)(bRow + row) * N + bCol + c8] = *(const ushort8_t*)&lds2[row * 136 + c8];
        }
    } else {  // EPI 1
        float* ldsf = (float*)smem;  // [128 cols][132]
        float bn[4];
        #pragma unroll
        for (int n = 0; n < 4; ++n) bn[n] = bias[bCol + wc + n * 16 + ln15];
        #pragma unroll
        for (int m = 0; m < 4; ++m)
            #pragma unroll
            for (int n = 0; n < 4; ++n) {
                int col = wc + n * 16 + ln15;
                #pragma unroll
                for (int r = 0; r < 4; ++r) {
                    int row = wr + m * 16 + kg * 4 + r;
                    float v = acc[m][n][r] + bn[n] + hbuf[(long)(bRow + row) * HID + bCol + col];
                    ldsf[col * 132 + row] = v;
                }
            }
        __syncthreads();
        float* O = (float*)outp;
        int b = bRow >> 12;
        int s0 = bRow & 4095;
        #pragma unroll
        for (int it = 0; it < 16; ++it) {
            int idx = (it << 8) + tid;
            int oc = idx >> 5, r4 = (idx & 31) << 2;
            *(float4*)&O[((long)(b * HID + bCol + oc)) * HWP + s0 + r4] = *(const float4*)&ldsf[oc * 132 + r4];
        }
    }
}

extern "C" void kernel_launch(void* const* d_in, const int* in_sizes, int n_in,
                              void* d_out, int out_size, void* d_ws, size_t ws_size,
                              hipStream_t stream)
{
    (void)in_sizes; (void)n_in; (void)out_size; (void)ws_size;
    const float* x     = (const float*)d_in[0];
    const float* xp    = (const float*)d_in[1];
    const float* w1    = (const float*)d_in[3];
    const float* b1    = (const float*)d_in[4];
    const float* w2    = (const float*)d_in[5];
    const float* b2    = (const float*)d_in[6];
    const float* w3    = (const float*)d_in[7];
    const float* b3    = (const float*)d_in[8];
    const float* alpha = (const float*)d_in[9];
    const float* g1    = (const float*)d_in[10];
    const float* be1   = (const float*)d_in[11];
    const float* g2    = (const float*)d_in[12];
    const float* be2   = (const float*)d_in[13];
    const float* pw    = (const float*)d_in[14];
    const float* pb    = (const float*)d_in[15];
    const float* fc1w  = (const float*)d_in[16];
    const float* fc1b  = (const float*)d_in[17];
    const float* fc2w  = (const float*)d_in[18];
    const float* fc2b  = (const float*)d_in[19];
    float* out = (float*)d_out;

    float* ws = (float*)d_ws;
    float* S0 = ws + 0 * SLOTF;
    float* S1 = ws + 1 * SLOTF;
    float* S2 = ws + 2 * SLOTF;
    float* S3 = ws + 3 * SLOTF;
    float* S4 = ws + 4 * SLOTF;
    float* S5 = ws + 5 * SLOTF;
    float* S6 = ws + 6 * SLOTF;

    float* RES  = S0;
    float* XN   = S1;                      // 16MB (S1-lower)
    u16*   M1x  = (u16*)S2;                // 16MB
    u16*   XF   = (u16*)S3;                // 16MB
    u16*   X1   = (u16*)S4;                // 32MB
    u16*   M1p  = (u16*)S2;                // 32MB (M1x dead)
    u16*   PF   = (u16*)S3;                // 32MB (XF dead)
    u16*   P3   = (u16*)S5;                // 32MB
    u16*   A2   = (u16*)S2;                // 32MB (M1p dead)
    u16*   O2b  = (u16*)S3;                // 32MB (PF dead)
    u16*   M2   = (u16*)S2;                // 32MB (A2 dead)
    float* Hb   = S6;                      // 32MB
    u16*   Mb16 = (u16*)S1;                // 16MB (XN dead)
    u16*   HIDB = (u16*)S2;                // 128MB spanning S2..S5

    // static region: S1-upper 16MB
    u16* TWB  = (u16*)(S1 + SLOTF / 2);
    u16* TW_F = TWB;                       // fwd hi(16K) + lo(16K)
    u16* TW_I = TWB + 32768;               // inv hi + lo
    u16* W1c  = TWB + 65536;               // 512x256
    u16* W3c  = W1c + 131072;              // 512x512
    u16* W2c  = W3c + 262144;              // 512x512
    u16* WB1  = W2c + 262144;              // 2048x256
    u16* WB2  = WB1 + 524288;              // 256x2048

    dim3 blk(256);

    // 0. static setup: twiddle tables + weight conversions
    tables_kernel<<<64, blk, 0, stream>>>(TWB);
    wcvt_kernel<<<128, blk, 0, stream>>>(w1, 128, W1c);
    wcvt_kernel<<<256, blk, 0, stream>>>(w3, 256, W3c);
    wcvt_kernel<<<256, blk, 0, stream>>>(w2, 256, W2c);
    f2bf_kernel<<<512, blk, 0, stream>>>(fc1w, WB1, MLPH * HID);
    f2bf_kernel<<<512, blk, 0, stream>>>(fc2w, WB2, HID * MLPH);

    // 1. LN1 and residual projection
    ln1_kernel<<<512, blk, 0, stream>>>(x, g1, be1, XN);
    resid_kernel<<<2048, blk, 0, stream>>>(x, pw, pb, RES);

    // 2-3. forward FFT2 of xn: W-axis then H-axis (MFMA)
    dftm_kernel<0, 0><<<512, blk, 0, stream>>>(XN, TW_F, M1x, nullptr,
        1, 524288L, 8192L, 0L, 128L, 0L, 1048576L, 16384L, 0L, 128L, 8192L);
    dftm_kernel<1, 0><<<512, blk, 0, stream>>>(M1x, TW_F, XF, nullptr,
        1, 1048576L, 128L, 0L, 16384L, 8192L, 1048576L, 256L, 0L, 16384L, 128L);
    // 4. complex GEMM w1 (K=2*128) -> X1 bf16 packed
    gemm_mfma_kernel<2><<<1024, blk, 0, stream>>>(XF, W1c, b1, nullptr,
        (void*)X1, NTOK, 512, 256);

    // 5-6. forward FFT2 of x_pangu (channel-major input)
    dftm_kernel<2, 0><<<1024, blk, 0, stream>>>(xp, TW_F, M1p, nullptr,
        2, 1048576L, 64L, 524288L, 4096L, 0L, 2097152L, 32768L, 128L, 256L, 16384L);
    dftm_kernel<1, 0><<<1024, blk, 0, stream>>>(M1p, TW_F, PF, nullptr,
        2, 2097152L, 256L, 128L, 32768L, 16384L, 2097152L, 512L, 128L, 32768L, 256L);
    // 7. complex GEMM w3 (K=2*256) -> P3 bf16 packed
    gemm_mfma_kernel<2><<<1024, blk, 0, stream>>>(PF, W3c, b3, nullptr,
        (void*)P3, NTOK, 512, 512);

    // 8. modulation + channel softmax -> A2 bf16
    mod_kernel<<<32768, blk, 0, stream>>>(X1, P3, alpha, A2);
    // 9. complex GEMM w2 + softshrink -> O2b bf16 packed
    gemm_mfma_kernel<4><<<1024, blk, 0, stream>>>(A2, W2c, b2, nullptr,
        (void*)O2b, NTOK, 512, 512);

    // 10-11. inverse FFT2: H-axis then W-axis (real out, fused +RES)
    dftm_kernel<1, 0><<<1024, blk, 0, stream>>>(O2b, TW_I, M2, nullptr,
        2, 2097152L, 512L, 128L, 32768L, 256L, 2097152L, 256L, 128L, 32768L, 16384L);
    dftm_kernel<1, 1><<<1024, blk, 0, stream>>>(M2, TW_I, Hb, RES,
        2, 2097152L, 32768L, 128L, 256L, 16384L, 1048576L, 16384L, 128L, 256L, 0L);

    // 12. LN2 -> bf16
    ln2_kernel<<<32768, blk, 0, stream>>>(Hb, g2, be2, Mb16);
    // 13. MLP fc1 (MFMA) + gelu -> bf16 hidden
    gemm_mfma_kernel<0><<<4096, blk, 0, stream>>>(Mb16, WB1, fc1b, nullptr,
        (void*)HIDB, NTOK, MLPH, HID);
    // 14. MLP fc2 (MFMA) + bias + h, transposed out
    gemm_mfma_kernel<1><<<512, blk, 0, stream>>>(HIDB, WB2, fc2b, Hb,
        (void*)out, NTOK, HID, MLPH);
}